// Round 2
// baseline (489.168 us; speedup 1.0000x reference)
//
#include <hip/hip_runtime.h>
#include <hip/hip_bf16.h>

#define Hdim 256
#define Tdim 256
#define Bdim 512
#define TT   32
#define NTILE (Tdim / TT)
#define NTHR 512

typedef __attribute__((ext_vector_type(8))) short s16x8;
typedef __attribute__((ext_vector_type(4))) float f32x4;
typedef unsigned short u16;
typedef unsigned int u32;

__device__ __forceinline__ u16 f2bf_rne(float x) {
    u32 u = __builtin_bit_cast(u32, x);
    u32 r = u + 0x7FFFu + ((u >> 16) & 1u);
    return (u16)(r >> 16);
}
__device__ __forceinline__ float bf2f(u16 h) {
    u32 u = ((u32)h) << 16;
    return __builtin_bit_cast(float, u);
}
__device__ __forceinline__ u32 cvt_pk_bf16(float lo, float hi) {
    u32 r;
    asm("v_cvt_pk_bf16_f32 %0, %1, %2" : "=v"(r) : "v"(lo), "v"(hi));
    return r;
}
__device__ __forceinline__ f32x4 mfma16(s16x8 a, s16x8 b, f32x4 c) {
    return __builtin_amdgcn_mfma_f32_16x16x32_bf16(a, b, c, 0, 0, 0);
}
__device__ __forceinline__ float fast_tanh(float z) {
    float e = __expf(2.0f * z);
    return 1.0f - 2.0f / (e + 1.0f);
}

// ---------------- prep: split weights into bf16 hi/lo, packed B-fragment layout --
// packed short index for W[o][k]: o16=o>>4, c=o&15, ks=k>>5, g=(k>>3)&3, j=k&7
//   dst = o16*4096 + ks*512 + g*128 + c*8 + j
// so a wave's (n,ks) fragment load is ptr + lane*8 -> fully coalesced 1KB.
__global__ __launch_bounds__(256) void prep_weights(
        const float* __restrict__ W_Ih, const float* __restrict__ W_oI,
        u16* __restrict__ Wp1h, u16* __restrict__ Wp1l,
        u16* __restrict__ Wp2h, u16* __restrict__ Wp2l) {
    int idx = blockIdx.x * 256 + threadIdx.x;   // = o*256 + k
    if (idx >= Hdim * Hdim) return;
    int o = idx >> 8, k = idx & 255;
    int dst = (o >> 4) * 4096 + (k >> 5) * 512 + ((k >> 3) & 3) * 128 + (o & 15) * 8 + (k & 7);
    float w = W_Ih[idx];
    u16 hi = f2bf_rne(w);
    Wp1h[dst] = hi;
    Wp1l[dst] = f2bf_rne(w - bf2f(hi));
    w = W_oI[idx];
    hi = f2bf_rne(w);
    Wp2h[dst] = hi;
    Wp2l[dst] = f2bf_rne(w - bf2f(hi));
}

// ---------------- prep: cp[b,o] = h_hat @ W_I^T + b_I ----------------
__global__ __launch_bounds__(256) void cp_kernel(
        const float* __restrict__ h_tilde, const float* __restrict__ c_t,
        const float* __restrict__ W_I, const float* __restrict__ b_I,
        float* __restrict__ cp) {
    int b = blockIdx.x;
    int tid = threadIdx.x, w = tid >> 6, lane = tid & 63;
    __shared__ float hh[2 * Hdim];
    for (int i = tid; i < 2 * Hdim; i += 256)
        hh[i] = (i < Hdim) ? h_tilde[b * Hdim + i] : c_t[b * Hdim + i - Hdim];
    __syncthreads();
    for (int o = w; o < Hdim; o += 4) {
        float s = 0.f;
        const float* wr = W_I + (size_t)o * (2 * Hdim);
        #pragma unroll
        for (int k = lane; k < 2 * Hdim; k += 64) s += hh[k] * wr[k];
        #pragma unroll
        for (int d = 1; d < 64; d <<= 1) s += __shfl_xor(s, d, 64);
        if (lane == 0) cp[b * Hdim + o] = s + b_I[o];
    }
}

// ---------------- fused main kernel: one block per batch row ----------------
// LDS ~77KB -> 2 blocks/CU (16 waves/CU).
__global__ __launch_bounds__(NTHR, 4) void attn_main(
        const float* __restrict__ hist, const float* __restrict__ dT,
        const float* __restrict__ dL, const float* __restrict__ cp,
        const u16* __restrict__ Wp1h, const u16* __restrict__ Wp1l,
        const u16* __restrict__ Wp2h, const u16* __restrict__ Wp2l,
        const float* __restrict__ wI1T, const float* __restrict__ wI1L,
        const float* __restrict__ b_oI, const float* __restrict__ v_t,
        float* __restrict__ out) {
    __shared__ u16 histbf_sh[2 * TT * Hdim];   // 32 KB, double-buffered, XOR-swizzled
    __shared__ u16 Ihi_sh[TT * Hdim];          // 16 KB
    __shared__ u16 Ilo_sh[TT * Hdim];          // 16 KB
    __shared__ float cpb[Hdim], wTl[Hdim], wLl[Hdim], bol[Hdim], vvl[Hdim];
    __shared__ float sc_part[8][TT];           // 1 KB
    __shared__ float scores_all[Tdim];         // 1 KB
    __shared__ float dtl[TT], dll[TT];
    __shared__ float sacc[4][Hdim];            // 4 KB (end-of-kernel combine only)

    const int b = blockIdx.x;
    const int tid = threadIdx.x;
    const int w = tid >> 6, lane = tid & 63;
    const int c = lane & 15, g = lane >> 4;
    const int ob = w * 32;
    const int wobg = w * 2;

    for (int i = tid; i < Hdim; i += NTHR) {
        cpb[i] = cp[b * Hdim + i];
        wTl[i] = wI1T[i];
        wLl[i] = wI1L[i];
        bol[i] = b_oI[i];
        vvl[i] = v_t[i];
    }

    // stage tile 0 (fp32 -> bf16, swizzled)
    {
        const int row = tid >> 4, colblk = (tid & 15) * 16;
        const float* src = hist + ((size_t)b * Tdim + row) * Hdim + colblk;
        float4 f0 = *(const float4*)(src + 0);
        float4 f1 = *(const float4*)(src + 4);
        float4 f2 = *(const float4*)(src + 8);
        float4 f3 = *(const float4*)(src + 12);
        uint4 ua = make_uint4(cvt_pk_bf16(f0.x, f0.y), cvt_pk_bf16(f0.z, f0.w),
                              cvt_pk_bf16(f1.x, f1.y), cvt_pk_bf16(f1.z, f1.w));
        uint4 ub = make_uint4(cvt_pk_bf16(f2.x, f2.y), cvt_pk_bf16(f2.z, f2.w),
                              cvt_pk_bf16(f3.x, f3.y), cvt_pk_bf16(f3.z, f3.w));
        char* dst = (char*)histbf_sh;
        const u32 bb = (u32)(row * 512 + colblk * 2);
        const u32 sz = (u32)((row & 7) << 4);
        *(uint4*)(dst + (bb ^ sz)) = ua;
        *(uint4*)(dst + ((bb + 16) ^ sz)) = ub;
        if (tid < TT) { dtl[tid] = dT[b * Tdim + tid]; dll[tid] = dL[b * Tdim + tid]; }
    }

    float m_run = -3.0e38f, l_run = 0.f;
    float s0 = 0.f, s1 = 0.f;                  // per-thread slice of s_t accumulator
    float pv = 0.f;
    const int q = w >> 1;                      // t-quarter for accum
    const int pp = ((w & 1) << 6) | lane;      // col-pair index 0..127
    const f32x4 fz = {0.f, 0.f, 0.f, 0.f};
    const u32 swzA = (u32)((c & 7) << 4);
    const u32 offA0 = (u32)(c * 512 + g * 16);
    const u32 offA1 = offA0 + 16 * 512;

    #pragma unroll 1
    for (int tile = 0; tile < NTILE; ++tile) {
        const int buf = tile & 1;
        const int t0 = tile * TT;
        __syncthreads();   // histbf[buf], dtl/dll ready; Ihi/Ilo free

        // ================= GEMM1: I = hist @ (Wh+Wl)^T (2-pass) =================
        f32x4 acc[2][2];
        acc[0][0] = fz; acc[0][1] = fz; acc[1][0] = fz; acc[1][1] = fz;
        {
            const char* hb = (const char*)histbf_sh + buf * (TT * Hdim * 2);
            #pragma unroll
            for (int ks = 0; ks < 8; ++ks) {
                const s16x8 a0 = *(const s16x8*)(hb + ((offA0 + ks * 64) ^ swzA));
                const s16x8 a1 = *(const s16x8*)(hb + ((offA1 + ks * 64) ^ swzA));
                #pragma unroll
                for (int n = 0; n < 2; ++n) {
                    const int wo = (wobg + n) * 4096 + ks * 512 + lane * 8;
                    const s16x8 bh = *(const s16x8*)(Wp1h + wo);
                    const s16x8 bl = *(const s16x8*)(Wp1l + wo);
                    acc[0][n] = mfma16(a0, bh, acc[0][n]);
                    acc[0][n] = mfma16(a0, bl, acc[0][n]);
                    acc[1][n] = mfma16(a1, bh, acc[1][n]);
                    acc[1][n] = mfma16(a1, bl, acc[1][n]);
                }
            }
        }
        // epilogue: add cp + dt*wT + dl*wL; pair-pack; split hi/lo bf16 into LDS
        #pragma unroll
        for (int n = 0; n < 2; ++n) {
            const int o = ob + n * 16 + c;
            const float base_ = cpb[o], wt = wTl[o], wl = wLl[o];
            const u32 ocol2 = (u32)((o & ~1) * 2);
            #pragma unroll
            for (int m = 0; m < 2; ++m) {
                #pragma unroll
                for (int r = 0; r < 4; ++r) {
                    const int row = m * 16 + g * 4 + r;
                    float z = acc[m][n][r] + base_ + dtl[row] * wt + dll[row] * wl;
                    float zsw = __shfl_xor(z, 1, 64);
                    float z0 = (c & 1) ? zsw : z;
                    float z1 = (c & 1) ? z : zsw;
                    u32 hi2 = cvt_pk_bf16(z0, z1);
                    const u32 byteoff = ((u32)(row * 512) + ocol2) ^ ((u32)((row & 7) << 4));
                    if (!(c & 1)) {
                        *(u32*)((char*)Ihi_sh + byteoff) = hi2;
                    } else {
                        float h0 = __builtin_bit_cast(float, hi2 << 16);
                        float h1 = __builtin_bit_cast(float, hi2 & 0xFFFF0000u);
                        u32 lo2 = cvt_pk_bf16(z0 - h0, z1 - h1);
                        *(u32*)((char*)Ilo_sh + byteoff) = lo2;
                    }
                }
            }
        }
        __syncthreads();   // Ihi/Ilo ready

        // ================= GEMM2: z = (Ihi+Ilo) @ (Wh+Wl)^T (3-pass) =============
        f32x4 acc2[2][2];
        acc2[0][0] = fz; acc2[0][1] = fz; acc2[1][0] = fz; acc2[1][1] = fz;
        {
            #pragma unroll
            for (int ks = 0; ks < 8; ++ks) {
                const s16x8 ah0 = *(const s16x8*)((const char*)Ihi_sh + ((offA0 + ks * 64) ^ swzA));
                const s16x8 ah1 = *(const s16x8*)((const char*)Ihi_sh + ((offA1 + ks * 64) ^ swzA));
                const s16x8 al0 = *(const s16x8*)((const char*)Ilo_sh + ((offA0 + ks * 64) ^ swzA));
                const s16x8 al1 = *(const s16x8*)((const char*)Ilo_sh + ((offA1 + ks * 64) ^ swzA));
                #pragma unroll
                for (int n = 0; n < 2; ++n) {
                    const int wo = (wobg + n) * 4096 + ks * 512 + lane * 8;
                    const s16x8 bh = *(const s16x8*)(Wp2h + wo);
                    const s16x8 bl = *(const s16x8*)(Wp2l + wo);
                    acc2[0][n] = mfma16(ah0, bh, acc2[0][n]);
                    acc2[0][n] = mfma16(ah0, bl, acc2[0][n]);
                    acc2[0][n] = mfma16(al0, bh, acc2[0][n]);
                    acc2[1][n] = mfma16(ah1, bh, acc2[1][n]);
                    acc2[1][n] = mfma16(ah1, bl, acc2[1][n]);
                    acc2[1][n] = mfma16(al1, bh, acc2[1][n]);
                }
            }
        }
        // epilogue: tanh, dot v, 16-lane reduce -> sc_part
        #pragma unroll
        for (int m = 0; m < 2; ++m) {
            #pragma unroll
            for (int r = 0; r < 4; ++r) {
                float s = 0.f;
                #pragma unroll
                for (int n = 0; n < 2; ++n) {
                    const int o = ob + n * 16 + c;
                    float z = acc2[m][n][r] + bol[o];
                    s += fast_tanh(z) * vvl[o];
                }
                s += __shfl_xor(s, 1, 64);
                s += __shfl_xor(s, 2, 64);
                s += __shfl_xor(s, 4, 64);
                s += __shfl_xor(s, 8, 64);
                if (c == 0) sc_part[w][m * 16 + g * 4 + r] = s;
            }
        }
        __syncthreads();   // sc_part ready

        // ========== merged: prefetch(k+1) | softmax (all waves, registers) | accum ==========
        const bool notlast = (tile + 1 < NTILE);
        float4 f0, f1, f2, f3;
        if (notlast) {   // issue global loads early; consume after compute
            const int row = tid >> 4, colblk = (tid & 15) * 16;
            const float* src = hist + ((size_t)b * Tdim + t0 + TT + row) * Hdim + colblk;
            f0 = *(const float4*)(src + 0);
            f1 = *(const float4*)(src + 4);
            f2 = *(const float4*)(src + 8);
            f3 = *(const float4*)(src + 12);
        }

        // softmax: every wave computes identical running stats in registers
        float sc = 0.f;
        if (lane < TT) {
            #pragma unroll
            for (int ww = 0; ww < 8; ++ww) sc += sc_part[ww][lane];
        }
        float scm = (lane < TT) ? sc : -3.0e38f;
        #pragma unroll
        for (int d = 1; d < 64; d <<= 1) scm = fmaxf(scm, __shfl_xor(scm, d, 64));
        const float m_new = fmaxf(m_run, scm);
        const float fac = __expf(m_run - m_new);
        pv = (lane < TT) ? __expf(sc - m_new) : 0.f;
        float ps = pv;
        #pragma unroll
        for (int d = 1; d < 64; d <<= 1) ps += __shfl_xor(ps, d, 64);
        l_run = l_run * fac + ps;
        m_run = m_new;
        if (w == 0 && lane < TT) scores_all[t0 + lane] = sc;

        // accum: this thread owns cols (2pp, 2pp+1), t in [8q, 8q+8)
        s0 *= fac; s1 *= fac;
        {
            const char* hb = (const char*)histbf_sh + buf * (TT * Hdim * 2);
            #pragma unroll
            for (int i = 0; i < 8; ++i) {
                const int t = q * 8 + i;
                const float pvt = __shfl(pv, t, 64);
                const u32 hw = *(const u32*)(hb + (((u32)(t * 512 + pp * 4)) ^ ((u32)((t & 7) << 4))));
                s0 += pvt * __builtin_bit_cast(float, hw << 16);
                s1 += pvt * __builtin_bit_cast(float, hw & 0xFFFF0000u);
            }
        }

        // write prefetched tile into the other buffer
        if (notlast) {
            uint4 ua = make_uint4(cvt_pk_bf16(f0.x, f0.y), cvt_pk_bf16(f0.z, f0.w),
                                  cvt_pk_bf16(f1.x, f1.y), cvt_pk_bf16(f1.z, f1.w));
            uint4 ub = make_uint4(cvt_pk_bf16(f2.x, f2.y), cvt_pk_bf16(f2.z, f2.w),
                                  cvt_pk_bf16(f3.x, f3.y), cvt_pk_bf16(f3.z, f3.w));
            const int row = tid >> 4, colblk = (tid & 15) * 16;
            char* dst = (char*)histbf_sh + (buf ^ 1) * (TT * Hdim * 2);
            const u32 bb = (u32)(row * 512 + colblk * 2);
            const u32 sz = (u32)((row & 7) << 4);
            *(uint4*)(dst + (bb ^ sz)) = ua;
            *(uint4*)(dst + ((bb + 16) ^ sz)) = ub;
            if (w == 0 && lane < TT) {
                dtl[lane] = dT[b * Tdim + t0 + TT + lane];
                dll[lane] = dL[b * Tdim + t0 + TT + lane];
            }
        }
    }

    // ---- final combine + outputs ----
    sacc[q][2 * pp] = s0;
    sacc[q][2 * pp + 1] = s1;
    __syncthreads();
    if (tid < Hdim) {
        const float inv_l = 1.0f / l_run;
        const float s = sacc[0][tid] + sacc[1][tid] + sacc[2][tid] + sacc[3][tid];
        out[b * Hdim + tid] = s * inv_l;
        out[Bdim * Hdim + b * Tdim + tid] = __expf(scores_all[tid] - m_run) * inv_l;
    }
}

extern "C" void kernel_launch(void* const* d_in, const int* in_sizes, int n_in,
                              void* d_out, int out_size, void* d_ws, size_t ws_size,
                              hipStream_t stream) {
    const float* h_tilde = (const float*)d_in[0];
    const float* c_t     = (const float*)d_in[1];
    const float* hist    = (const float*)d_in[2];
    const float* dT      = (const float*)d_in[3];
    const float* dL      = (const float*)d_in[4];
    const float* W_I     = (const float*)d_in[5];
    const float* W_Ih    = (const float*)d_in[6];
    const float* W_I1T   = (const float*)d_in[7];
    const float* W_I1L   = (const float*)d_in[8];
    const float* b_I     = (const float*)d_in[9];
    const float* W_oI    = (const float*)d_in[10];
    const float* b_oI    = (const float*)d_in[11];
    const float* v_t     = (const float*)d_in[12];
    float* out = (float*)d_out;

    char* ws = (char*)d_ws;
    float* cp  = (float*)ws;                          // 512 KB
    u16* Wp1h = (u16*)(ws + 524288);                  // 128 KB each
    u16* Wp1l = (u16*)(ws + 524288 + 131072);
    u16* Wp2h = (u16*)(ws + 524288 + 2 * 131072);
    u16* Wp2l = (u16*)(ws + 524288 + 3 * 131072);

    prep_weights<<<dim3(256), dim3(256), 0, stream>>>(W_Ih, W_oI, Wp1h, Wp1l, Wp2h, Wp2l);
    cp_kernel<<<dim3(Bdim), dim3(256), 0, stream>>>(h_tilde, c_t, W_I, b_I, cp);
    attn_main<<<dim3(Bdim), dim3(NTHR), 0, stream>>>(hist, dT, dL, cp,
                                                     Wp1h, Wp1l, Wp2h, Wp2l,
                                                     W_I1T, W_I1L, b_oI, v_t, out);
}

// Round 3
// 434.636 us; speedup vs baseline: 1.1255x; 1.1255x over previous
//
#include <hip/hip_runtime.h>
#include <hip/hip_bf16.h>

#define Hdim 256
#define Tdim 256
#define Bdim 512
#define TT   32
#define NTILE (Tdim / TT)
#define NTHR 512

typedef __attribute__((ext_vector_type(8))) short s16x8;
typedef __attribute__((ext_vector_type(4))) float f32x4;
typedef unsigned short u16;
typedef unsigned int u32;

__device__ __forceinline__ u16 f2bf_rne(float x) {
    u32 u = __builtin_bit_cast(u32, x);
    u32 r = u + 0x7FFFu + ((u >> 16) & 1u);
    return (u16)(r >> 16);
}
__device__ __forceinline__ float bf2f(u16 h) {
    u32 u = ((u32)h) << 16;
    return __builtin_bit_cast(float, u);
}
__device__ __forceinline__ u32 cvt_pk_bf16(float lo, float hi) {
    u32 r;
    asm("v_cvt_pk_bf16_f32 %0, %1, %2" : "=v"(r) : "v"(lo), "v"(hi));
    return r;
}
__device__ __forceinline__ f32x4 mfma16(s16x8 a, s16x8 b, f32x4 c) {
    return __builtin_amdgcn_mfma_f32_16x16x32_bf16(a, b, c, 0, 0, 0);
}
__device__ __forceinline__ float fast_tanh(float z) {
    float e = __expf(2.0f * z);
    return 1.0f - 2.0f / (e + 1.0f);
}

// ---------------- prep: split weights into bf16 hi/lo, packed B-fragment layout --
// packed short index for W[o][k]: o16=o>>4, c=o&15, ks=k>>5, g=(k>>3)&3, j=k&7
//   dst = o16*4096 + ks*512 + g*128 + c*8 + j
// so a wave's (n,ks) fragment load is ptr + lane*8 -> fully coalesced 1KB.
__global__ __launch_bounds__(256) void prep_weights(
        const float* __restrict__ W_Ih, const float* __restrict__ W_oI,
        u16* __restrict__ Wp1h, u16* __restrict__ Wp1l,
        u16* __restrict__ Wp2h, u16* __restrict__ Wp2l) {
    int idx = blockIdx.x * 256 + threadIdx.x;   // = o*256 + k
    if (idx >= Hdim * Hdim) return;
    int o = idx >> 8, k = idx & 255;
    int dst = (o >> 4) * 4096 + (k >> 5) * 512 + ((k >> 3) & 3) * 128 + (o & 15) * 8 + (k & 7);
    float w = W_Ih[idx];
    u16 hi = f2bf_rne(w);
    Wp1h[dst] = hi;
    Wp1l[dst] = f2bf_rne(w - bf2f(hi));
    w = W_oI[idx];
    hi = f2bf_rne(w);
    Wp2h[dst] = hi;
    Wp2l[dst] = f2bf_rne(w - bf2f(hi));
}

// ---------------- prep: cp[b,o] = h_hat @ W_I^T + b_I ----------------
__global__ __launch_bounds__(256) void cp_kernel(
        const float* __restrict__ h_tilde, const float* __restrict__ c_t,
        const float* __restrict__ W_I, const float* __restrict__ b_I,
        float* __restrict__ cp) {
    int b = blockIdx.x;
    int tid = threadIdx.x, w = tid >> 6, lane = tid & 63;
    __shared__ float hh[2 * Hdim];
    for (int i = tid; i < 2 * Hdim; i += 256)
        hh[i] = (i < Hdim) ? h_tilde[b * Hdim + i] : c_t[b * Hdim + i - Hdim];
    __syncthreads();
    for (int o = w; o < Hdim; o += 4) {
        float s = 0.f;
        const float* wr = W_I + (size_t)o * (2 * Hdim);
        #pragma unroll
        for (int k = lane; k < 2 * Hdim; k += 64) s += hh[k] * wr[k];
        #pragma unroll
        for (int d = 1; d < 64; d <<= 1) s += __shfl_xor(s, d, 64);
        if (lane == 0) cp[b * Hdim + o] = s + b_I[o];
    }
}

// ---------------- fused main kernel: one block per batch row ----------------
// LDS ~77KB + VGPR<=128 -> 2 blocks/CU (16 waves/CU).
__global__ __launch_bounds__(NTHR, 4) void attn_main(
        const float* __restrict__ hist, const float* __restrict__ dT,
        const float* __restrict__ dL, const float* __restrict__ cp,
        const u16* __restrict__ Wp1h, const u16* __restrict__ Wp1l,
        const u16* __restrict__ Wp2h, const u16* __restrict__ Wp2l,
        const float* __restrict__ wI1T, const float* __restrict__ wI1L,
        const float* __restrict__ b_oI, const float* __restrict__ v_t,
        float* __restrict__ out) {
    __shared__ u16 histbf_sh[2 * TT * Hdim];   // 32 KB, double-buffered, XOR-swizzled
    __shared__ u16 Ihi_sh[TT * Hdim];          // 16 KB
    __shared__ u16 Ilo_sh[TT * Hdim];          // 16 KB
    __shared__ float cpb[Hdim], wTl[Hdim], wLl[Hdim], bol[Hdim], vvl[Hdim];
    __shared__ float sc_part[8][TT];           // 1 KB
    __shared__ float scores_all[Tdim];         // 1 KB
    __shared__ float dtl[TT], dll[TT];
    __shared__ float sacc[4][Hdim];            // 4 KB (end-of-kernel combine only)

    const int b = blockIdx.x;
    const int tid = threadIdx.x;
    const int w = tid >> 6, lane = tid & 63;
    const int c = lane & 15, g = lane >> 4;
    const int ob = w * 32;
    const int wobg = w * 2;

    for (int i = tid; i < Hdim; i += NTHR) {
        cpb[i] = cp[b * Hdim + i];
        wTl[i] = wI1T[i];
        wLl[i] = wI1L[i];
        bol[i] = b_oI[i];
        vvl[i] = v_t[i];
    }

    const int srow = tid >> 4, scolblk = (tid & 15) * 16;   // staging coords
    const u32 sbb = (u32)(srow * 512 + scolblk * 2);
    const u32 ssz = (u32)((srow & 7) << 4);

    // stage tile 0 (fp32 -> bf16, swizzled); tight scopes to bound live regs
    {
        const float* src = hist + ((size_t)b * Tdim + srow) * Hdim + scolblk;
        char* dst = (char*)histbf_sh;
        {
            float4 f0 = *(const float4*)(src + 0);
            float4 f1 = *(const float4*)(src + 4);
            uint4 ua = make_uint4(cvt_pk_bf16(f0.x, f0.y), cvt_pk_bf16(f0.z, f0.w),
                                  cvt_pk_bf16(f1.x, f1.y), cvt_pk_bf16(f1.z, f1.w));
            *(uint4*)(dst + (sbb ^ ssz)) = ua;
        }
        {
            float4 f2 = *(const float4*)(src + 8);
            float4 f3 = *(const float4*)(src + 12);
            uint4 ub = make_uint4(cvt_pk_bf16(f2.x, f2.y), cvt_pk_bf16(f2.z, f2.w),
                                  cvt_pk_bf16(f3.x, f3.y), cvt_pk_bf16(f3.z, f3.w));
            *(uint4*)(dst + ((sbb + 16) ^ ssz)) = ub;
        }
        if (tid < TT) { dtl[tid] = dT[b * Tdim + tid]; dll[tid] = dL[b * Tdim + tid]; }
    }

    float m_run = -3.0e38f, l_run = 0.f;
    float s0 = 0.f, s1 = 0.f;                  // per-thread slice of s_t accumulator
    const int q = w >> 1;                      // t-quarter for accum
    const int pp = ((w & 1) << 6) | lane;      // col-pair index 0..127
    const f32x4 fz = {0.f, 0.f, 0.f, 0.f};
    const u32 swzA = (u32)((c & 7) << 4);
    const u32 offA0 = (u32)(c * 512 + g * 16);
    const u32 offA1 = offA0 + 16 * 512;

    #pragma unroll 1
    for (int tile = 0; tile < NTILE; ++tile) {
        const int buf = tile & 1;
        const int t0 = tile * TT;
        __syncthreads();   // histbf[buf], dtl/dll ready; Ihi/Ilo free

        // ================= GEMM1: I = hist @ (Wh+Wl)^T (2-pass) =================
        f32x4 acc[2][2];
        acc[0][0] = fz; acc[0][1] = fz; acc[1][0] = fz; acc[1][1] = fz;
        {
            const char* hb = (const char*)histbf_sh + buf * (TT * Hdim * 2);
            #pragma unroll
            for (int ks = 0; ks < 8; ++ks) {
                const s16x8 a0 = *(const s16x8*)(hb + ((offA0 + ks * 64) ^ swzA));
                const s16x8 a1 = *(const s16x8*)(hb + ((offA1 + ks * 64) ^ swzA));
                #pragma unroll
                for (int n = 0; n < 2; ++n) {
                    const int wo = (wobg + n) * 4096 + ks * 512 + lane * 8;
                    const s16x8 bh = *(const s16x8*)(Wp1h + wo);
                    const s16x8 bl = *(const s16x8*)(Wp1l + wo);
                    acc[0][n] = mfma16(a0, bh, acc[0][n]);
                    acc[0][n] = mfma16(a0, bl, acc[0][n]);
                    acc[1][n] = mfma16(a1, bh, acc[1][n]);
                    acc[1][n] = mfma16(a1, bl, acc[1][n]);
                }
            }
        }
        // epilogue: add cp + dt*wT + dl*wL; pair-pack; split hi/lo bf16 into LDS
        #pragma unroll
        for (int n = 0; n < 2; ++n) {
            const int o = ob + n * 16 + c;
            const float base_ = cpb[o], wt = wTl[o], wl = wLl[o];
            const u32 ocol2 = (u32)((o & ~1) * 2);
            #pragma unroll
            for (int m = 0; m < 2; ++m) {
                #pragma unroll
                for (int r = 0; r < 4; ++r) {
                    const int row = m * 16 + g * 4 + r;
                    float z = acc[m][n][r] + base_ + dtl[row] * wt + dll[row] * wl;
                    float zsw = __shfl_xor(z, 1, 64);
                    float z0 = (c & 1) ? zsw : z;
                    float z1 = (c & 1) ? z : zsw;
                    u32 hi2 = cvt_pk_bf16(z0, z1);
                    const u32 byteoff = ((u32)(row * 512) + ocol2) ^ ((u32)((row & 7) << 4));
                    if (!(c & 1)) {
                        *(u32*)((char*)Ihi_sh + byteoff) = hi2;
                    } else {
                        float h0 = __builtin_bit_cast(float, hi2 << 16);
                        float h1 = __builtin_bit_cast(float, hi2 & 0xFFFF0000u);
                        u32 lo2 = cvt_pk_bf16(z0 - h0, z1 - h1);
                        *(u32*)((char*)Ilo_sh + byteoff) = lo2;
                    }
                }
            }
        }
        __syncthreads();   // Ihi/Ilo ready

        // ================= GEMM2: z = (Ihi+Ilo) @ (Wh+Wl)^T (3-pass) =============
        f32x4 acc2[2][2];
        acc2[0][0] = fz; acc2[0][1] = fz; acc2[1][0] = fz; acc2[1][1] = fz;
        {
            #pragma unroll
            for (int ks = 0; ks < 8; ++ks) {
                const s16x8 ah0 = *(const s16x8*)((const char*)Ihi_sh + ((offA0 + ks * 64) ^ swzA));
                const s16x8 ah1 = *(const s16x8*)((const char*)Ihi_sh + ((offA1 + ks * 64) ^ swzA));
                const s16x8 al0 = *(const s16x8*)((const char*)Ilo_sh + ((offA0 + ks * 64) ^ swzA));
                const s16x8 al1 = *(const s16x8*)((const char*)Ilo_sh + ((offA1 + ks * 64) ^ swzA));
                #pragma unroll
                for (int n = 0; n < 2; ++n) {
                    const int wo = (wobg + n) * 4096 + ks * 512 + lane * 8;
                    const s16x8 bh = *(const s16x8*)(Wp2h + wo);
                    const s16x8 bl = *(const s16x8*)(Wp2l + wo);
                    acc2[0][n] = mfma16(ah0, bh, acc2[0][n]);
                    acc2[0][n] = mfma16(ah0, bl, acc2[0][n]);
                    acc2[0][n] = mfma16(al0, bh, acc2[0][n]);
                    acc2[1][n] = mfma16(ah1, bh, acc2[1][n]);
                    acc2[1][n] = mfma16(ah1, bl, acc2[1][n]);
                    acc2[1][n] = mfma16(al1, bh, acc2[1][n]);
                }
            }
        }
        // epilogue: tanh, dot v, 16-lane reduce -> sc_part
        #pragma unroll
        for (int m = 0; m < 2; ++m) {
            #pragma unroll
            for (int r = 0; r < 4; ++r) {
                float s = 0.f;
                #pragma unroll
                for (int n = 0; n < 2; ++n) {
                    const int o = ob + n * 16 + c;
                    float z = acc2[m][n][r] + bol[o];
                    s += fast_tanh(z) * vvl[o];
                }
                s += __shfl_xor(s, 1, 64);
                s += __shfl_xor(s, 2, 64);
                s += __shfl_xor(s, 4, 64);
                s += __shfl_xor(s, 8, 64);
                if (c == 0) sc_part[w][m * 16 + g * 4 + r] = s;
            }
        }
        __syncthreads();   // sc_part ready

        // ========== phase 4: softmax (all waves, registers) | stage k+1 | accum ==========
        // softmax: every wave computes identical running stats in registers
        float sc = 0.f;
        if (lane < TT) {
            #pragma unroll
            for (int ww = 0; ww < 8; ++ww) sc += sc_part[ww][lane];
        }
        float scm = (lane < TT) ? sc : -3.0e38f;
        #pragma unroll
        for (int d = 1; d < 64; d <<= 1) scm = fmaxf(scm, __shfl_xor(scm, d, 64));
        const float m_new = fmaxf(m_run, scm);
        const float fac = __expf(m_run - m_new);
        float pv = (lane < TT) ? __expf(sc - m_new) : 0.f;
        float ps = pv;
        #pragma unroll
        for (int d = 1; d < 64; d <<= 1) ps += __shfl_xor(ps, d, 64);
        l_run = l_run * fac + ps;
        m_run = m_new;
        if (w == 0 && lane < TT) scores_all[t0 + lane] = sc;

        // stage next tile (fp32->bf16, swizzled) into the other buffer.
        // Tightly scoped temporaries: <=10 live VGPRs, no long-held prefetch regs.
        if (tile + 1 < NTILE) {
            const float* src = hist + ((size_t)b * Tdim + t0 + TT + srow) * Hdim + scolblk;
            char* dst = (char*)histbf_sh + (buf ^ 1) * (TT * Hdim * 2);
            {
                float4 f0 = *(const float4*)(src + 0);
                float4 f1 = *(const float4*)(src + 4);
                uint4 ua = make_uint4(cvt_pk_bf16(f0.x, f0.y), cvt_pk_bf16(f0.z, f0.w),
                                      cvt_pk_bf16(f1.x, f1.y), cvt_pk_bf16(f1.z, f1.w));
                *(uint4*)(dst + (sbb ^ ssz)) = ua;
            }
            {
                float4 f2 = *(const float4*)(src + 8);
                float4 f3 = *(const float4*)(src + 12);
                uint4 ub = make_uint4(cvt_pk_bf16(f2.x, f2.y), cvt_pk_bf16(f2.z, f2.w),
                                      cvt_pk_bf16(f3.x, f3.y), cvt_pk_bf16(f3.z, f3.w));
                *(uint4*)(dst + ((sbb + 16) ^ ssz)) = ub;
            }
            if (w == 0 && lane < TT) {
                dtl[lane] = dT[b * Tdim + t0 + TT + lane];
                dll[lane] = dL[b * Tdim + t0 + TT + lane];
            }
        }

        // accum: this thread owns cols (2pp, 2pp+1), t in [8q, 8q+8)
        s0 *= fac; s1 *= fac;
        {
            const char* hb = (const char*)histbf_sh + buf * (TT * Hdim * 2);
            #pragma unroll
            for (int i = 0; i < 8; ++i) {
                const int t = q * 8 + i;
                const float pvt = __shfl(pv, t, 64);
                const u32 hw = *(const u32*)(hb + (((u32)(t * 512 + pp * 4)) ^ ((u32)((t & 7) << 4))));
                s0 += pvt * __builtin_bit_cast(float, hw << 16);
                s1 += pvt * __builtin_bit_cast(float, hw & 0xFFFF0000u);
            }
        }
    }

    // ---- final combine + outputs ----
    sacc[q][2 * pp] = s0;
    sacc[q][2 * pp + 1] = s1;
    __syncthreads();
    if (tid < Hdim) {
        const float inv_l = 1.0f / l_run;
        const float s = sacc[0][tid] + sacc[1][tid] + sacc[2][tid] + sacc[3][tid];
        out[b * Hdim + tid] = s * inv_l;
        out[Bdim * Hdim + b * Tdim + tid] = __expf(scores_all[tid] - m_run) * inv_l;
    }
}

extern "C" void kernel_launch(void* const* d_in, const int* in_sizes, int n_in,
                              void* d_out, int out_size, void* d_ws, size_t ws_size,
                              hipStream_t stream) {
    const float* h_tilde = (const float*)d_in[0];
    const float* c_t     = (const float*)d_in[1];
    const float* hist    = (const float*)d_in[2];
    const float* dT      = (const float*)d_in[3];
    const float* dL      = (const float*)d_in[4];
    const float* W_I     = (const float*)d_in[5];
    const float* W_Ih    = (const float*)d_in[6];
    const float* W_I1T   = (const float*)d_in[7];
    const float* W_I1L   = (const float*)d_in[8];
    const float* b_I     = (const float*)d_in[9];
    const float* W_oI    = (const float*)d_in[10];
    const float* b_oI    = (const float*)d_in[11];
    const float* v_t     = (const float*)d_in[12];
    float* out = (float*)d_out;

    char* ws = (char*)d_ws;
    float* cp  = (float*)ws;                          // 512 KB
    u16* Wp1h = (u16*)(ws + 524288);                  // 128 KB each
    u16* Wp1l = (u16*)(ws + 524288 + 131072);
    u16* Wp2h = (u16*)(ws + 524288 + 2 * 131072);
    u16* Wp2l = (u16*)(ws + 524288 + 3 * 131072);

    prep_weights<<<dim3(256), dim3(256), 0, stream>>>(W_Ih, W_oI, Wp1h, Wp1l, Wp2h, Wp2l);
    cp_kernel<<<dim3(Bdim), dim3(256), 0, stream>>>(h_tilde, c_t, W_I, b_I, cp);
    attn_main<<<dim3(Bdim), dim3(NTHR), 0, stream>>>(hist, dT, dL, cp,
                                                     Wp1h, Wp1l, Wp2h, Wp2l,
                                                     W_I1T, W_I1L, b_oI, v_t, out);
}

// Round 4
// 433.001 us; speedup vs baseline: 1.1297x; 1.0038x over previous
//
#include <hip/hip_runtime.h>
#include <hip/hip_bf16.h>

#define Hdim 256
#define Tdim 256
#define Bdim 512
#define TT   32
#define NTILE (Tdim / TT)
#define NTHR 512

typedef __attribute__((ext_vector_type(8))) short s16x8;
typedef __attribute__((ext_vector_type(4))) float f32x4;
typedef unsigned short u16;
typedef unsigned int u32;

__device__ __forceinline__ u16 f2bf_rne(float x) {
    u32 u = __builtin_bit_cast(u32, x);
    u32 r = u + 0x7FFFu + ((u >> 16) & 1u);
    return (u16)(r >> 16);
}
__device__ __forceinline__ float bf2f(u16 h) {
    u32 u = ((u32)h) << 16;
    return __builtin_bit_cast(float, u);
}
__device__ __forceinline__ u32 cvt_pk_bf16(float lo, float hi) {
    u32 r;
    asm("v_cvt_pk_bf16_f32 %0, %1, %2" : "=v"(r) : "v"(lo), "v"(hi));
    return r;
}
__device__ __forceinline__ f32x4 mfma16(s16x8 a, s16x8 b, f32x4 c) {
    return __builtin_amdgcn_mfma_f32_16x16x32_bf16(a, b, c, 0, 0, 0);
}
__device__ __forceinline__ float fast_tanh(float z) {
    float e = __expf(2.0f * z);
    return 1.0f - 2.0f / (e + 1.0f);
}

// ---------------- prep: split weights into bf16 hi/lo, packed B-fragment layout --
// packed short index for W[o][k]: o16=o>>4, c=o&15, ks=k>>5, g=(k>>3)&3, j=k&7
//   dst = o16*4096 + ks*512 + g*128 + c*8 + j
// so a wave's (n,ks) fragment load is ptr + lane*8 -> fully coalesced 1KB.
__global__ __launch_bounds__(256) void prep_weights(
        const float* __restrict__ W_Ih, const float* __restrict__ W_oI,
        u16* __restrict__ Wp1h, u16* __restrict__ Wp1l,
        u16* __restrict__ Wp2h, u16* __restrict__ Wp2l) {
    int idx = blockIdx.x * 256 + threadIdx.x;   // = o*256 + k
    if (idx >= Hdim * Hdim) return;
    int o = idx >> 8, k = idx & 255;
    int dst = (o >> 4) * 4096 + (k >> 5) * 512 + ((k >> 3) & 3) * 128 + (o & 15) * 8 + (k & 7);
    float w = W_Ih[idx];
    u16 hi = f2bf_rne(w);
    Wp1h[dst] = hi;
    Wp1l[dst] = f2bf_rne(w - bf2f(hi));
    w = W_oI[idx];
    hi = f2bf_rne(w);
    Wp2h[dst] = hi;
    Wp2l[dst] = f2bf_rne(w - bf2f(hi));
}

// ---------------- prep: cp[b,o] = h_hat @ W_I^T + b_I ----------------
__global__ __launch_bounds__(256) void cp_kernel(
        const float* __restrict__ h_tilde, const float* __restrict__ c_t,
        const float* __restrict__ W_I, const float* __restrict__ b_I,
        float* __restrict__ cp) {
    int b = blockIdx.x;
    int tid = threadIdx.x, w = tid >> 6, lane = tid & 63;
    __shared__ float hh[2 * Hdim];
    for (int i = tid; i < 2 * Hdim; i += 256)
        hh[i] = (i < Hdim) ? h_tilde[b * Hdim + i] : c_t[b * Hdim + i - Hdim];
    __syncthreads();
    for (int o = w; o < Hdim; o += 4) {
        float s = 0.f;
        const float* wr = W_I + (size_t)o * (2 * Hdim);
        #pragma unroll
        for (int k = lane; k < 2 * Hdim; k += 64) s += hh[k] * wr[k];
        #pragma unroll
        for (int d = 1; d < 64; d <<= 1) s += __shfl_xor(s, d, 64);
        if (lane == 0) cp[b * Hdim + o] = s + b_I[o];
    }
}

// ---------------- fused main kernel: one block per batch row ----------------
// LDS ~77KB -> 2 blocks/CU. amdgpu_waves_per_eu(4) => reg cap 128/wave
// (launch_bounds(512,4) was compiled as a 64-reg cap -> massive spills in r2/r3).
__global__ __launch_bounds__(NTHR) __attribute__((amdgpu_waves_per_eu(4))) void attn_main(
        const float* __restrict__ hist, const float* __restrict__ dT,
        const float* __restrict__ dL, const float* __restrict__ cp,
        const u16* __restrict__ Wp1h, const u16* __restrict__ Wp1l,
        const u16* __restrict__ Wp2h, const u16* __restrict__ Wp2l,
        const float* __restrict__ wI1T, const float* __restrict__ wI1L,
        const float* __restrict__ b_oI, const float* __restrict__ v_t,
        float* __restrict__ out) {
    __shared__ u16 histbf_sh[2 * TT * Hdim];   // 32 KB, double-buffered, XOR-swizzled
    __shared__ u16 Ihi_sh[TT * Hdim];          // 16 KB
    __shared__ u16 Ilo_sh[TT * Hdim];          // 16 KB
    __shared__ float cpb[Hdim], wTl[Hdim], wLl[Hdim], bol[Hdim], vvl[Hdim];
    __shared__ float sc_part[8][TT];           // 1 KB
    __shared__ float scores_all[Tdim];         // 1 KB
    __shared__ float dtl[TT], dll[TT];
    __shared__ float sacc[4][Hdim];            // 4 KB (end-of-kernel combine only)

    const int b = blockIdx.x;
    const int tid = threadIdx.x;
    const int w = tid >> 6, lane = tid & 63;
    const int c = lane & 15, g = lane >> 4;
    const int ob = w * 32;
    const int wobg = w * 2;

    for (int i = tid; i < Hdim; i += NTHR) {
        cpb[i] = cp[b * Hdim + i];
        wTl[i] = wI1T[i];
        wLl[i] = wI1L[i];
        bol[i] = b_oI[i];
        vvl[i] = v_t[i];
    }

    const int srow = tid >> 4, scolblk = (tid & 15) * 16;   // staging coords
    const u32 sbb = (u32)(srow * 512 + scolblk * 2);
    const u32 ssz = (u32)((srow & 7) << 4);

    // stage tile 0 (fp32 -> bf16, swizzled); tight scopes to bound live regs
    {
        const float* src = hist + ((size_t)b * Tdim + srow) * Hdim + scolblk;
        char* dst = (char*)histbf_sh;
        {
            float4 f0 = *(const float4*)(src + 0);
            float4 f1 = *(const float4*)(src + 4);
            uint4 ua = make_uint4(cvt_pk_bf16(f0.x, f0.y), cvt_pk_bf16(f0.z, f0.w),
                                  cvt_pk_bf16(f1.x, f1.y), cvt_pk_bf16(f1.z, f1.w));
            *(uint4*)(dst + (sbb ^ ssz)) = ua;
        }
        {
            float4 f2 = *(const float4*)(src + 8);
            float4 f3 = *(const float4*)(src + 12);
            uint4 ub = make_uint4(cvt_pk_bf16(f2.x, f2.y), cvt_pk_bf16(f2.z, f2.w),
                                  cvt_pk_bf16(f3.x, f3.y), cvt_pk_bf16(f3.z, f3.w));
            *(uint4*)(dst + ((sbb + 16) ^ ssz)) = ub;
        }
        if (tid < TT) { dtl[tid] = dT[b * Tdim + tid]; dll[tid] = dL[b * Tdim + tid]; }
    }

    float m_run = -3.0e38f, l_run = 0.f;
    float s0 = 0.f, s1 = 0.f;                  // per-thread slice of s_t accumulator
    const int q = w >> 1;                      // t-quarter for accum
    const int pp = ((w & 1) << 6) | lane;      // col-pair index 0..127
    const f32x4 fz = {0.f, 0.f, 0.f, 0.f};
    const u32 swzA = (u32)((c & 7) << 4);
    const u32 offA0 = (u32)(c * 512 + g * 16);
    const u32 offA1 = offA0 + 16 * 512;

    #pragma unroll 1
    for (int tile = 0; tile < NTILE; ++tile) {
        const int buf = tile & 1;
        const int t0 = tile * TT;
        __syncthreads();   // histbf[buf], dtl/dll ready; Ihi/Ilo free

        // ================= GEMM1: I = hist @ (Wh+Wl)^T (2-pass) =================
        f32x4 acc[2][2];
        acc[0][0] = fz; acc[0][1] = fz; acc[1][0] = fz; acc[1][1] = fz;
        {
            const char* hb = (const char*)histbf_sh + buf * (TT * Hdim * 2);
            #pragma unroll
            for (int ks = 0; ks < 8; ++ks) {
                const s16x8 a0 = *(const s16x8*)(hb + ((offA0 + ks * 64) ^ swzA));
                const s16x8 a1 = *(const s16x8*)(hb + ((offA1 + ks * 64) ^ swzA));
                #pragma unroll
                for (int n = 0; n < 2; ++n) {
                    const int wo = (wobg + n) * 4096 + ks * 512 + lane * 8;
                    const s16x8 bh = *(const s16x8*)(Wp1h + wo);
                    const s16x8 bl = *(const s16x8*)(Wp1l + wo);
                    acc[0][n] = mfma16(a0, bh, acc[0][n]);
                    acc[0][n] = mfma16(a0, bl, acc[0][n]);
                    acc[1][n] = mfma16(a1, bh, acc[1][n]);
                    acc[1][n] = mfma16(a1, bl, acc[1][n]);
                }
            }
        }
        // epilogue: add cp + dt*wT + dl*wL; pair-pack; split hi/lo bf16 into LDS
        #pragma unroll
        for (int n = 0; n < 2; ++n) {
            const int o = ob + n * 16 + c;
            const float base_ = cpb[o], wt = wTl[o], wl = wLl[o];
            const u32 ocol2 = (u32)((o & ~1) * 2);
            #pragma unroll
            for (int m = 0; m < 2; ++m) {
                #pragma unroll
                for (int r = 0; r < 4; ++r) {
                    const int row = m * 16 + g * 4 + r;
                    float z = acc[m][n][r] + base_ + dtl[row] * wt + dll[row] * wl;
                    float zsw = __shfl_xor(z, 1, 64);
                    float z0 = (c & 1) ? zsw : z;
                    float z1 = (c & 1) ? z : zsw;
                    u32 hi2 = cvt_pk_bf16(z0, z1);
                    const u32 byteoff = ((u32)(row * 512) + ocol2) ^ ((u32)((row & 7) << 4));
                    if (!(c & 1)) {
                        *(u32*)((char*)Ihi_sh + byteoff) = hi2;
                    } else {
                        float h0 = __builtin_bit_cast(float, hi2 << 16);
                        float h1 = __builtin_bit_cast(float, hi2 & 0xFFFF0000u);
                        u32 lo2 = cvt_pk_bf16(z0 - h0, z1 - h1);
                        *(u32*)((char*)Ilo_sh + byteoff) = lo2;
                    }
                }
            }
        }
        __syncthreads();   // Ihi/Ilo ready

        // ================= GEMM2: z = (Ihi+Ilo) @ (Wh+Wl)^T (3-pass) =============
        f32x4 acc2[2][2];
        acc2[0][0] = fz; acc2[0][1] = fz; acc2[1][0] = fz; acc2[1][1] = fz;
        {
            #pragma unroll
            for (int ks = 0; ks < 8; ++ks) {
                const s16x8 ah0 = *(const s16x8*)((const char*)Ihi_sh + ((offA0 + ks * 64) ^ swzA));
                const s16x8 ah1 = *(const s16x8*)((const char*)Ihi_sh + ((offA1 + ks * 64) ^ swzA));
                const s16x8 al0 = *(const s16x8*)((const char*)Ilo_sh + ((offA0 + ks * 64) ^ swzA));
                const s16x8 al1 = *(const s16x8*)((const char*)Ilo_sh + ((offA1 + ks * 64) ^ swzA));
                #pragma unroll
                for (int n = 0; n < 2; ++n) {
                    const int wo = (wobg + n) * 4096 + ks * 512 + lane * 8;
                    const s16x8 bh = *(const s16x8*)(Wp2h + wo);
                    const s16x8 bl = *(const s16x8*)(Wp2l + wo);
                    acc2[0][n] = mfma16(ah0, bh, acc2[0][n]);
                    acc2[0][n] = mfma16(ah0, bl, acc2[0][n]);
                    acc2[0][n] = mfma16(al0, bh, acc2[0][n]);
                    acc2[1][n] = mfma16(ah1, bh, acc2[1][n]);
                    acc2[1][n] = mfma16(ah1, bl, acc2[1][n]);
                    acc2[1][n] = mfma16(al1, bh, acc2[1][n]);
                }
            }
        }
        // epilogue: tanh, dot v, 16-lane reduce -> sc_part
        #pragma unroll
        for (int m = 0; m < 2; ++m) {
            #pragma unroll
            for (int r = 0; r < 4; ++r) {
                float s = 0.f;
                #pragma unroll
                for (int n = 0; n < 2; ++n) {
                    const int o = ob + n * 16 + c;
                    float z = acc2[m][n][r] + bol[o];
                    s += fast_tanh(z) * vvl[o];
                }
                s += __shfl_xor(s, 1, 64);
                s += __shfl_xor(s, 2, 64);
                s += __shfl_xor(s, 4, 64);
                s += __shfl_xor(s, 8, 64);
                if (c == 0) sc_part[w][m * 16 + g * 4 + r] = s;
            }
        }
        __syncthreads();   // sc_part ready

        // ========== phase 4: softmax (all waves, registers) | stage k+1 | accum ==========
        // softmax: every wave computes identical running stats in registers
        float sc = 0.f;
        if (lane < TT) {
            #pragma unroll
            for (int ww = 0; ww < 8; ++ww) sc += sc_part[ww][lane];
        }
        float scm = (lane < TT) ? sc : -3.0e38f;
        #pragma unroll
        for (int d = 1; d < 64; d <<= 1) scm = fmaxf(scm, __shfl_xor(scm, d, 64));
        const float m_new = fmaxf(m_run, scm);
        const float fac = __expf(m_run - m_new);
        float pv = (lane < TT) ? __expf(sc - m_new) : 0.f;
        float ps = pv;
        #pragma unroll
        for (int d = 1; d < 64; d <<= 1) ps += __shfl_xor(ps, d, 64);
        l_run = l_run * fac + ps;
        m_run = m_new;
        if (w == 0 && lane < TT) scores_all[t0 + lane] = sc;

        // stage next tile (fp32->bf16, swizzled) into the other buffer.
        // Tightly scoped temporaries: <=10 live VGPRs, no long-held prefetch regs.
        if (tile + 1 < NTILE) {
            const float* src = hist + ((size_t)b * Tdim + t0 + TT + srow) * Hdim + scolblk;
            char* dst = (char*)histbf_sh + (buf ^ 1) * (TT * Hdim * 2);
            {
                float4 f0 = *(const float4*)(src + 0);
                float4 f1 = *(const float4*)(src + 4);
                uint4 ua = make_uint4(cvt_pk_bf16(f0.x, f0.y), cvt_pk_bf16(f0.z, f0.w),
                                      cvt_pk_bf16(f1.x, f1.y), cvt_pk_bf16(f1.z, f1.w));
                *(uint4*)(dst + (sbb ^ ssz)) = ua;
            }
            {
                float4 f2 = *(const float4*)(src + 8);
                float4 f3 = *(const float4*)(src + 12);
                uint4 ub = make_uint4(cvt_pk_bf16(f2.x, f2.y), cvt_pk_bf16(f2.z, f2.w),
                                      cvt_pk_bf16(f3.x, f3.y), cvt_pk_bf16(f3.z, f3.w));
                *(uint4*)(dst + ((sbb + 16) ^ ssz)) = ub;
            }
            if (w == 0 && lane < TT) {
                dtl[lane] = dT[b * Tdim + t0 + TT + lane];
                dll[lane] = dL[b * Tdim + t0 + TT + lane];
            }
        }

        // accum: this thread owns cols (2pp, 2pp+1), t in [8q, 8q+8)
        s0 *= fac; s1 *= fac;
        {
            const char* hb = (const char*)histbf_sh + buf * (TT * Hdim * 2);
            #pragma unroll
            for (int i = 0; i < 8; ++i) {
                const int t = q * 8 + i;
                const float pvt = __shfl(pv, t, 64);
                const u32 hw = *(const u32*)(hb + (((u32)(t * 512 + pp * 4)) ^ ((u32)((t & 7) << 4))));
                s0 += pvt * __builtin_bit_cast(float, hw << 16);
                s1 += pvt * __builtin_bit_cast(float, hw & 0xFFFF0000u);
            }
        }
    }

    // ---- final combine + outputs ----
    sacc[q][2 * pp] = s0;
    sacc[q][2 * pp + 1] = s1;
    __syncthreads();
    if (tid < Hdim) {
        const float inv_l = 1.0f / l_run;
        const float s = sacc[0][tid] + sacc[1][tid] + sacc[2][tid] + sacc[3][tid];
        out[b * Hdim + tid] = s * inv_l;
        out[Bdim * Hdim + b * Tdim + tid] = __expf(scores_all[tid] - m_run) * inv_l;
    }
}

extern "C" void kernel_launch(void* const* d_in, const int* in_sizes, int n_in,
                              void* d_out, int out_size, void* d_ws, size_t ws_size,
                              hipStream_t stream) {
    const float* h_tilde = (const float*)d_in[0];
    const float* c_t     = (const float*)d_in[1];
    const float* hist    = (const float*)d_in[2];
    const float* dT      = (const float*)d_in[3];
    const float* dL      = (const float*)d_in[4];
    const float* W_I     = (const float*)d_in[5];
    const float* W_Ih    = (const float*)d_in[6];
    const float* W_I1T   = (const float*)d_in[7];
    const float* W_I1L   = (const float*)d_in[8];
    const float* b_I     = (const float*)d_in[9];
    const float* W_oI    = (const float*)d_in[10];
    const float* b_oI    = (const float*)d_in[11];
    const float* v_t     = (const float*)d_in[12];
    float* out = (float*)d_out;

    char* ws = (char*)d_ws;
    float* cp  = (float*)ws;                          // 512 KB
    u16* Wp1h = (u16*)(ws + 524288);                  // 128 KB each
    u16* Wp1l = (u16*)(ws + 524288 + 131072);
    u16* Wp2h = (u16*)(ws + 524288 + 2 * 131072);
    u16* Wp2l = (u16*)(ws + 524288 + 3 * 131072);

    prep_weights<<<dim3(256), dim3(256), 0, stream>>>(W_Ih, W_oI, Wp1h, Wp1l, Wp2h, Wp2l);
    cp_kernel<<<dim3(Bdim), dim3(256), 0, stream>>>(h_tilde, c_t, W_I, b_I, cp);
    attn_main<<<dim3(Bdim), dim3(NTHR), 0, stream>>>(hist, dT, dL, cp,
                                                     Wp1h, Wp1l, Wp2h, Wp2l,
                                                     W_I1T, W_I1L, b_oI, v_t, out);
}

// Round 5
// 221.590 us; speedup vs baseline: 2.2075x; 1.9541x over previous
//
#include <hip/hip_runtime.h>
#include <hip/hip_bf16.h>

#define Hdim 256
#define Tdim 256
#define Bdim 512
#define TT   64
#define NTILE (Tdim / TT)   // 4
#define NTHR 512

typedef __attribute__((ext_vector_type(8))) short s16x8;
typedef __attribute__((ext_vector_type(4))) float f32x4;
typedef unsigned short u16;
typedef unsigned int u32;

__device__ __forceinline__ u16 f2bf_rne(float x) {
    u32 u = __builtin_bit_cast(u32, x);
    u32 r = u + 0x7FFFu + ((u >> 16) & 1u);
    return (u16)(r >> 16);
}
__device__ __forceinline__ float bf2f(u16 h) {
    u32 u = ((u32)h) << 16;
    return __builtin_bit_cast(float, u);
}
__device__ __forceinline__ u32 cvt_pk_bf16(float lo, float hi) {
    u32 r;
    asm("v_cvt_pk_bf16_f32 %0, %1, %2" : "=v"(r) : "v"(lo), "v"(hi));
    return r;
}
__device__ __forceinline__ f32x4 mfma16(s16x8 a, s16x8 b, f32x4 c) {
    return __builtin_amdgcn_mfma_f32_16x16x32_bf16(a, b, c, 0, 0, 0);
}
__device__ __forceinline__ float fast_tanh(float z) {
    float e = __expf(2.0f * z);
    return 1.0f - 2.0f / (e + 1.0f);
}

// ---------------- prep: split weights into bf16 hi/lo, packed B-fragment layout --
// dst = o16*4096 + ks*512 + g*128 + c*8 + j  (lane*8 per (n,ks) frag -> coalesced)
__global__ __launch_bounds__(256) void prep_weights(
        const float* __restrict__ W_Ih, const float* __restrict__ W_oI,
        u16* __restrict__ Wp1h, u16* __restrict__ Wp1l,
        u16* __restrict__ Wp2h, u16* __restrict__ Wp2l) {
    int idx = blockIdx.x * 256 + threadIdx.x;   // = o*256 + k
    if (idx >= Hdim * Hdim) return;
    int o = idx >> 8, k = idx & 255;
    int dst = (o >> 4) * 4096 + (k >> 5) * 512 + ((k >> 3) & 3) * 128 + (o & 15) * 8 + (k & 7);
    float w = W_Ih[idx];
    u16 hi = f2bf_rne(w);
    Wp1h[dst] = hi;
    Wp1l[dst] = f2bf_rne(w - bf2f(hi));
    w = W_oI[idx];
    hi = f2bf_rne(w);
    Wp2h[dst] = hi;
    Wp2l[dst] = f2bf_rne(w - bf2f(hi));
}

// ---------------- prep: cp[b,o] = h_hat @ W_I^T + b_I ----------------
__global__ __launch_bounds__(256) void cp_kernel(
        const float* __restrict__ h_tilde, const float* __restrict__ c_t,
        const float* __restrict__ W_I, const float* __restrict__ b_I,
        float* __restrict__ cp) {
    int b = blockIdx.x;
    int tid = threadIdx.x, w = tid >> 6, lane = tid & 63;
    __shared__ float hh[2 * Hdim];
    for (int i = tid; i < 2 * Hdim; i += 256)
        hh[i] = (i < Hdim) ? h_tilde[b * Hdim + i] : c_t[b * Hdim + i - Hdim];
    __syncthreads();
    for (int o = w; o < Hdim; o += 4) {
        float s = 0.f;
        const float* wr = W_I + (size_t)o * (2 * Hdim);
        #pragma unroll
        for (int k = lane; k < 2 * Hdim; k += 64) s += hh[k] * wr[k];
        #pragma unroll
        for (int d = 1; d < 64; d <<= 1) s += __shfl_xor(s, d, 64);
        if (lane == 0) cp[b * Hdim + o] = s + b_I[o];
    }
}

// ---------------- pass 1: scores[b, t0..t0+63] per block (independent) ----------
// LDS union: [0,32K) hist bf16 (phase A) then Ihi (phase B); [32K,64K) Ilo.
// 68KB total -> 2 blocks/CU. No occupancy attribute: unconstrained regalloc
// (launch_bounds(512,4)/waves_per_eu(4) both force a 64-arch-VGPR cap -> spills).
__global__ __launch_bounds__(NTHR) void scores_kernel(
        const float* __restrict__ hist, const float* __restrict__ dT,
        const float* __restrict__ dL, const float* __restrict__ cp,
        const u16* __restrict__ Wp1h, const u16* __restrict__ Wp1l,
        const u16* __restrict__ Wp2h, const u16* __restrict__ Wp2l,
        const float* __restrict__ wI1T, const float* __restrict__ wI1L,
        const float* __restrict__ b_oI, const float* __restrict__ v_t,
        float* __restrict__ scores) {
    __shared__ u16 lds_u[32768];               // 64 KB union region
    __shared__ float dtl[TT], dll[TT];
    __shared__ float sc_part[8][TT];           // 2 KB

    const int bid = blockIdx.x;
    const int b = bid >> 2;                    // NTILE = 4
    const int t0 = (bid & (NTILE - 1)) * TT;
    const int tid = threadIdx.x;
    const int w = tid >> 6, lane = tid & 63;
    const int c = lane & 15, g = lane >> 4;
    const int ob = w * 32;

    // per-lane epilogue constants (n = 0,1 -> o = ob + n*16 + c)
    float cpv[2], wtv[2], wlv[2], bov[2], vvv[2];
    #pragma unroll
    for (int n = 0; n < 2; ++n) {
        const int o = ob + n * 16 + c;
        cpv[n] = cp[b * Hdim + o];
        wtv[n] = wI1T[o];
        wlv[n] = wI1L[o];
        bov[n] = b_oI[o];
        vvv[n] = v_t[o];
    }
    if (tid < TT) {
        dtl[tid] = dT[b * Tdim + t0 + tid];
        dll[tid] = dL[b * Tdim + t0 + tid];
    }

    // ---- stage hist tile: 64 rows x 256 cols fp32 -> bf16 swizzled ----
    {
        const int row = tid >> 3;              // 8 threads per row
        const int colblk = (tid & 7) * 32;     // 32 floats each
        const float* src = hist + ((size_t)b * Tdim + t0 + row) * Hdim + colblk;
        char* dst = (char*)lds_u;
        const u32 bb = (u32)(row * 512 + colblk * 2);
        const u32 sz = (u32)((row & 7) << 4);
        {
            float4 f0 = *(const float4*)(src + 0);
            float4 f1 = *(const float4*)(src + 4);
            uint4 ua = make_uint4(cvt_pk_bf16(f0.x, f0.y), cvt_pk_bf16(f0.z, f0.w),
                                  cvt_pk_bf16(f1.x, f1.y), cvt_pk_bf16(f1.z, f1.w));
            *(uint4*)(dst + ((bb + 0) ^ sz)) = ua;
        }
        {
            float4 f0 = *(const float4*)(src + 8);
            float4 f1 = *(const float4*)(src + 12);
            uint4 ua = make_uint4(cvt_pk_bf16(f0.x, f0.y), cvt_pk_bf16(f0.z, f0.w),
                                  cvt_pk_bf16(f1.x, f1.y), cvt_pk_bf16(f1.z, f1.w));
            *(uint4*)(dst + ((bb + 16) ^ sz)) = ua;
        }
        {
            float4 f0 = *(const float4*)(src + 16);
            float4 f1 = *(const float4*)(src + 20);
            uint4 ua = make_uint4(cvt_pk_bf16(f0.x, f0.y), cvt_pk_bf16(f0.z, f0.w),
                                  cvt_pk_bf16(f1.x, f1.y), cvt_pk_bf16(f1.z, f1.w));
            *(uint4*)(dst + ((bb + 32) ^ sz)) = ua;
        }
        {
            float4 f0 = *(const float4*)(src + 24);
            float4 f1 = *(const float4*)(src + 28);
            uint4 ua = make_uint4(cvt_pk_bf16(f0.x, f0.y), cvt_pk_bf16(f0.z, f0.w),
                                  cvt_pk_bf16(f1.x, f1.y), cvt_pk_bf16(f1.z, f1.w));
            *(uint4*)(dst + ((bb + 48) ^ sz)) = ua;
        }
    }
    __syncthreads();

    const f32x4 fz = {0.f, 0.f, 0.f, 0.f};
    const u32 swzA = (u32)((c & 7) << 4);
    const int wobg = w * 2;

    // ================= GEMM1: I = hist @ (Wh+Wl)^T (2-pass split bf16) ==========
    f32x4 acc[4][2];
    #pragma unroll
    for (int m = 0; m < 4; ++m) { acc[m][0] = fz; acc[m][1] = fz; }
    {
        const char* hb = (const char*)lds_u;
        #pragma unroll
        for (int ks = 0; ks < 8; ++ks) {
            s16x8 a[4];
            #pragma unroll
            for (int m = 0; m < 4; ++m)
                a[m] = *(const s16x8*)(hb + (((u32)((m * 16 + c) * 512 + g * 16 + ks * 64)) ^ swzA));
            #pragma unroll
            for (int n = 0; n < 2; ++n) {
                const int wo = (wobg + n) * 4096 + ks * 512 + lane * 8;
                const s16x8 bh = *(const s16x8*)(Wp1h + wo);
                const s16x8 bl = *(const s16x8*)(Wp1l + wo);
                #pragma unroll
                for (int m = 0; m < 4; ++m) {
                    acc[m][n] = mfma16(a[m], bh, acc[m][n]);
                    acc[m][n] = mfma16(a[m], bl, acc[m][n]);
                }
            }
        }
    }
    __syncthreads();   // all hist LDS reads complete; region reusable for Ihi

    // ---- epilogue 1: z -> hi/lo bf16 into LDS (Ihi over hist region, Ilo above) --
    {
        char* Ihi_b = (char*)lds_u;
        char* Ilo_b = (char*)lds_u + 32768;
        #pragma unroll
        for (int n = 0; n < 2; ++n) {
            const int o = ob + n * 16 + c;
            const float base_ = cpv[n], wt = wtv[n], wl = wlv[n];
            const u32 ocol2 = (u32)((o & ~1) * 2);
            #pragma unroll
            for (int m = 0; m < 4; ++m) {
                #pragma unroll
                for (int r = 0; r < 4; ++r) {
                    const int row = m * 16 + g * 4 + r;
                    float z = acc[m][n][r] + base_ + dtl[row] * wt + dll[row] * wl;
                    float zsw = __shfl_xor(z, 1, 64);
                    float z0 = (c & 1) ? zsw : z;
                    float z1 = (c & 1) ? z : zsw;
                    u32 hi2 = cvt_pk_bf16(z0, z1);
                    const u32 byteoff = ((u32)(row * 512) + ocol2) ^ ((u32)((row & 7) << 4));
                    if (!(c & 1)) {
                        *(u32*)(Ihi_b + byteoff) = hi2;
                    } else {
                        float h0 = __builtin_bit_cast(float, hi2 << 16);
                        float h1 = __builtin_bit_cast(float, hi2 & 0xFFFF0000u);
                        u32 lo2 = cvt_pk_bf16(z0 - h0, z1 - h1);
                        *(u32*)(Ilo_b + byteoff) = lo2;
                    }
                }
            }
        }
    }
    __syncthreads();   // Ihi/Ilo ready

    // ================= GEMM2: z = (Ihi+Ilo) @ (Wh+Wl)^T (3-pass) ================
    f32x4 acc2[4][2];
    #pragma unroll
    for (int m = 0; m < 4; ++m) { acc2[m][0] = fz; acc2[m][1] = fz; }
    {
        const char* Ihi_b = (const char*)lds_u;
        const char* Ilo_b = (const char*)lds_u + 32768;
        #pragma unroll
        for (int ks = 0; ks < 8; ++ks) {
            s16x8 ah[4], al[4];
            #pragma unroll
            for (int m = 0; m < 4; ++m) {
                const u32 ad = ((u32)((m * 16 + c) * 512 + g * 16 + ks * 64)) ^ swzA;
                ah[m] = *(const s16x8*)(Ihi_b + ad);
                al[m] = *(const s16x8*)(Ilo_b + ad);
            }
            #pragma unroll
            for (int n = 0; n < 2; ++n) {
                const int wo = (wobg + n) * 4096 + ks * 512 + lane * 8;
                const s16x8 bh = *(const s16x8*)(Wp2h + wo);
                const s16x8 bl = *(const s16x8*)(Wp2l + wo);
                #pragma unroll
                for (int m = 0; m < 4; ++m) {
                    acc2[m][n] = mfma16(ah[m], bh, acc2[m][n]);
                    acc2[m][n] = mfma16(ah[m], bl, acc2[m][n]);
                    acc2[m][n] = mfma16(al[m], bh, acc2[m][n]);
                }
            }
        }
    }

    // ---- epilogue 2: tanh, dot v, 16-lane reduce, cross-wave sum, write scores --
    #pragma unroll
    for (int m = 0; m < 4; ++m) {
        #pragma unroll
        for (int r = 0; r < 4; ++r) {
            float s = 0.f;
            #pragma unroll
            for (int n = 0; n < 2; ++n) {
                float z = acc2[m][n][r] + bov[n];
                s += fast_tanh(z) * vvv[n];
            }
            s += __shfl_xor(s, 1, 64);
            s += __shfl_xor(s, 2, 64);
            s += __shfl_xor(s, 4, 64);
            s += __shfl_xor(s, 8, 64);
            if (c == 0) sc_part[w][m * 16 + g * 4 + r] = s;
        }
    }
    __syncthreads();
    if (tid < TT) {
        float s = 0.f;
        #pragma unroll
        for (int ww = 0; ww < 8; ++ww) s += sc_part[ww][tid];
        scores[b * Tdim + t0 + tid] = s;
    }
}

// ---------------- pass 2: softmax + alpha + s_t = alpha^T . hist ----------------
// scores live in the alpha slot of out; overwritten in-place with alpha.
__global__ __launch_bounds__(512) void finish_kernel(
        const float* __restrict__ hist, float* __restrict__ out) {
    const int b = blockIdx.x;
    const int tid = threadIdx.x;
    const int w = tid >> 6, lane = tid & 63;
    __shared__ float al_sh[Tdim];
    __shared__ float wred[4], wsum[4];
    __shared__ float part[Hdim];

    float* scores = out + Bdim * Hdim;
    float sc = 0.f;
    if (tid < Tdim) {
        sc = scores[b * Tdim + tid];
        float mx = sc;
        #pragma unroll
        for (int d = 1; d < 64; d <<= 1) mx = fmaxf(mx, __shfl_xor(mx, d, 64));
        if (lane == 0) wred[w] = mx;
    }
    __syncthreads();
    const float mx = fmaxf(fmaxf(wred[0], wred[1]), fmaxf(wred[2], wred[3]));
    float e = 0.f;
    if (tid < Tdim) {
        e = __expf(sc - mx);
        float ss = e;
        #pragma unroll
        for (int d = 1; d < 64; d <<= 1) ss += __shfl_xor(ss, d, 64);
        if (lane == 0) wsum[w] = ss;
    }
    __syncthreads();
    const float l = wsum[0] + wsum[1] + wsum[2] + wsum[3];
    if (tid < Tdim) {
        const float a = e / l;
        al_sh[tid] = a;
        scores[b * Tdim + tid] = a;   // alpha output (in-place over scores)
    }
    __syncthreads();

    // weighted sum: thread (h = tid&255, half = tid>>8) sums t in [half*128, +128)
    const int h = tid & 255, half = tid >> 8;
    const float* hp = hist + (size_t)b * (Tdim * Hdim) + (size_t)half * 128 * Hdim + h;
    float s0 = 0.f, s1 = 0.f, s2 = 0.f, s3 = 0.f;
    #pragma unroll 4
    for (int t = 0; t < 128; t += 4) {
        const int tb = half * 128 + t;
        s0 += al_sh[tb + 0] * hp[(size_t)(t + 0) * Hdim];
        s1 += al_sh[tb + 1] * hp[(size_t)(t + 1) * Hdim];
        s2 += al_sh[tb + 2] * hp[(size_t)(t + 2) * Hdim];
        s3 += al_sh[tb + 3] * hp[(size_t)(t + 3) * Hdim];
    }
    const float s = (s0 + s1) + (s2 + s3);
    if (half == 0) part[h] = s;
    __syncthreads();
    if (half == 1) out[b * Hdim + h] = part[h] + s;
}

extern "C" void kernel_launch(void* const* d_in, const int* in_sizes, int n_in,
                              void* d_out, int out_size, void* d_ws, size_t ws_size,
                              hipStream_t stream) {
    const float* h_tilde = (const float*)d_in[0];
    const float* c_t     = (const float*)d_in[1];
    const float* hist    = (const float*)d_in[2];
    const float* dT      = (const float*)d_in[3];
    const float* dL      = (const float*)d_in[4];
    const float* W_I     = (const float*)d_in[5];
    const float* W_Ih    = (const float*)d_in[6];
    const float* W_I1T   = (const float*)d_in[7];
    const float* W_I1L   = (const float*)d_in[8];
    const float* b_I     = (const float*)d_in[9];
    const float* W_oI    = (const float*)d_in[10];
    const float* b_oI    = (const float*)d_in[11];
    const float* v_t     = (const float*)d_in[12];
    float* out = (float*)d_out;

    char* ws = (char*)d_ws;
    float* cp  = (float*)ws;                          // 512 KB
    u16* Wp1h = (u16*)(ws + 524288);                  // 128 KB each
    u16* Wp1l = (u16*)(ws + 524288 + 131072);
    u16* Wp2h = (u16*)(ws + 524288 + 2 * 131072);
    u16* Wp2l = (u16*)(ws + 524288 + 3 * 131072);
    float* scores = out + Bdim * Hdim;                // raw scores into alpha slot

    prep_weights<<<dim3(256), dim3(256), 0, stream>>>(W_Ih, W_oI, Wp1h, Wp1l, Wp2h, Wp2l);
    cp_kernel<<<dim3(Bdim), dim3(256), 0, stream>>>(h_tilde, c_t, W_I, b_I, cp);
    scores_kernel<<<dim3(Bdim * NTILE), dim3(NTHR), 0, stream>>>(
        hist, dT, dL, cp, Wp1h, Wp1l, Wp2h, Wp2l, W_I1T, W_I1L, b_oI, v_t, scores);
    finish_kernel<<<dim3(Bdim), dim3(512), 0, stream>>>(hist, out);
}

// Round 6
// 209.069 us; speedup vs baseline: 2.3397x; 1.0599x over previous
//
#include <hip/hip_runtime.h>
#include <hip/hip_bf16.h>

#define Hdim 256
#define Tdim 256
#define Bdim 512
#define TT   128
#define NTILE (Tdim / TT)   // 2
#define NTHR 1024

typedef __attribute__((ext_vector_type(8))) short s16x8;
typedef __attribute__((ext_vector_type(4))) float f32x4;
typedef unsigned short u16;
typedef unsigned int u32;

__device__ __forceinline__ u16 f2bf_rne(float x) {
    u32 u = __builtin_bit_cast(u32, x);
    u32 r = u + 0x7FFFu + ((u >> 16) & 1u);
    return (u16)(r >> 16);
}
__device__ __forceinline__ float bf2f(u16 h) {
    u32 u = ((u32)h) << 16;
    return __builtin_bit_cast(float, u);
}
__device__ __forceinline__ u32 cvt_pk_bf16(float lo, float hi) {
    u32 r;
    asm("v_cvt_pk_bf16_f32 %0, %1, %2" : "=v"(r) : "v"(lo), "v"(hi));
    return r;
}
__device__ __forceinline__ f32x4 mfma16(s16x8 a, s16x8 b, f32x4 c) {
    return __builtin_amdgcn_mfma_f32_16x16x32_bf16(a, b, c, 0, 0, 0);
}
__device__ __forceinline__ float fast_tanh(float z) {
    float e = __expf(2.0f * z);
    return 1.0f - 2.0f / (e + 1.0f);
}

// ---------------- prep: split weights into bf16 hi/lo, packed B-fragment layout --
// dst = o16*4096 + ks*512 + g*128 + c*8 + j  (lane*8 per (o16,ks) frag -> coalesced)
__global__ __launch_bounds__(256) void prep_weights(
        const float* __restrict__ W_Ih, const float* __restrict__ W_oI,
        u16* __restrict__ Wp1h, u16* __restrict__ Wp1l,
        u16* __restrict__ Wp2h, u16* __restrict__ Wp2l) {
    int idx = blockIdx.x * 256 + threadIdx.x;   // = o*256 + k
    if (idx >= Hdim * Hdim) return;
    int o = idx >> 8, k = idx & 255;
    int dst = (o >> 4) * 4096 + (k >> 5) * 512 + ((k >> 3) & 3) * 128 + (o & 15) * 8 + (k & 7);
    float w = W_Ih[idx];
    u16 hi = f2bf_rne(w);
    Wp1h[dst] = hi;
    Wp1l[dst] = f2bf_rne(w - bf2f(hi));
    w = W_oI[idx];
    hi = f2bf_rne(w);
    Wp2h[dst] = hi;
    Wp2l[dst] = f2bf_rne(w - bf2f(hi));
}

// ---------------- prep: cp[b,o] = h_hat @ W_I^T + b_I ----------------
__global__ __launch_bounds__(256) void cp_kernel(
        const float* __restrict__ h_tilde, const float* __restrict__ c_t,
        const float* __restrict__ W_I, const float* __restrict__ b_I,
        float* __restrict__ cp) {
    int b = blockIdx.x;
    int tid = threadIdx.x, w = tid >> 6, lane = tid & 63;
    __shared__ float hh[2 * Hdim];
    for (int i = tid; i < 2 * Hdim; i += 256)
        hh[i] = (i < Hdim) ? h_tilde[b * Hdim + i] : c_t[b * Hdim + i - Hdim];
    __syncthreads();
    for (int o = w; o < Hdim; o += 4) {
        float s = 0.f;
        const float* wr = W_I + (size_t)o * (2 * Hdim);
        #pragma unroll
        for (int k = lane; k < 2 * Hdim; k += 64) s += hh[k] * wr[k];
        #pragma unroll
        for (int d = 1; d < 64; d <<= 1) s += __shfl_xor(s, d, 64);
        if (lane == 0) cp[b * Hdim + o] = s + b_I[o];
    }
}

// ---------------- pass 1: scores for a 128-row tile per block ----------------
// 1024 threads = 16 waves; wave w owns o-cols [w*16, w*16+16), m = 0..7 row-frags.
// LDS: [0,64K) hist bf16 (GEMM1 A) -> reused as Ihi after GEMM1; [64K,128K) Ilo.
// ~140KB -> 1 block/CU (16 waves). Weight L2 traffic halves vs TT=64.
// Staging split into 2 k-halves; half-1 loads issued early (hide under GEMM1a).
__global__ __launch_bounds__(NTHR) void scores_kernel(
        const float* __restrict__ hist, const float* __restrict__ dT,
        const float* __restrict__ dL, const float* __restrict__ cp,
        const u16* __restrict__ Wp1h, const u16* __restrict__ Wp1l,
        const u16* __restrict__ Wp2h, const u16* __restrict__ Wp2l,
        const float* __restrict__ wI1T, const float* __restrict__ wI1L,
        const float* __restrict__ b_oI, const float* __restrict__ v_t,
        float* __restrict__ scores) {
    __shared__ u16 lds_u[2 * TT * Hdim];       // 128 KB: hist/Ihi + Ilo
    __shared__ float dtl[TT], dll[TT];         // 1 KB
    __shared__ float sc_part[16][TT];          // 8 KB

    const int bid = blockIdx.x;
    const int b = bid >> 1;                    // NTILE = 2
    const int t0 = (bid & 1) * TT;
    const int tid = threadIdx.x;
    const int w = tid >> 6, lane = tid & 63;
    const int c = lane & 15, g = lane >> 4;
    const int o = w * 16 + c;                  // this thread's output column

    // per-lane epilogue constants
    const float cpv = cp[b * Hdim + o];
    const float wtv = wI1T[o];
    const float wlv = wI1L[o];
    const float bov = b_oI[o];
    const float vvv = v_t[o];
    if (tid < TT) {
        dtl[tid] = dT[b * Tdim + t0 + tid];
        dll[tid] = dL[b * Tdim + t0 + tid];
    }

    // ---- staging geometry: row = tid>>3 (0..127), 8 threads x 16 cols per half --
    const int srow = tid >> 3;
    const int scol0 = (tid & 7) * 16;          // col within half
    const u32 sbb = (u32)(srow * 512);
    const u32 ssz = (u32)((srow & 7) << 4);
    const float* srcb = hist + ((size_t)b * Tdim + t0 + srow) * Hdim;

    // stage half 0 (cols 0..127)
    {
        float4 f0 = *(const float4*)(srcb + scol0 + 0);
        float4 f1 = *(const float4*)(srcb + scol0 + 4);
        float4 f2 = *(const float4*)(srcb + scol0 + 8);
        float4 f3 = *(const float4*)(srcb + scol0 + 12);
        uint4 ua = make_uint4(cvt_pk_bf16(f0.x, f0.y), cvt_pk_bf16(f0.z, f0.w),
                              cvt_pk_bf16(f1.x, f1.y), cvt_pk_bf16(f1.z, f1.w));
        uint4 ub = make_uint4(cvt_pk_bf16(f2.x, f2.y), cvt_pk_bf16(f2.z, f2.w),
                              cvt_pk_bf16(f3.x, f3.y), cvt_pk_bf16(f3.z, f3.w));
        char* dst = (char*)lds_u;
        *(uint4*)(dst + ((sbb + scol0 * 2 + 0) ^ ssz)) = ua;
        *(uint4*)(dst + ((sbb + scol0 * 2 + 16) ^ ssz)) = ub;
    }
    // issue half-1 loads now; consume after GEMM1a (T14 issue-early/write-late)
    float4 h1a = *(const float4*)(srcb + 128 + scol0 + 0);
    float4 h1b = *(const float4*)(srcb + 128 + scol0 + 4);
    float4 h1c = *(const float4*)(srcb + 128 + scol0 + 8);
    float4 h1d = *(const float4*)(srcb + 128 + scol0 + 12);

    __syncthreads();   // half-0 + dtl/dll ready

    const f32x4 fz = {0.f, 0.f, 0.f, 0.f};
    const u32 swzA = (u32)((c & 7) << 4);
    const int wbase = w * 4096;

    f32x4 acc[8];
    #pragma unroll
    for (int m = 0; m < 8; ++m) acc[m] = fz;

    // ================= GEMM1a: ks 0..3 (k-cols 0..127) =================
    #pragma unroll
    for (int ks = 0; ks < 4; ++ks) {
        const int wo = wbase + ks * 512 + lane * 8;
        const s16x8 bh = *(const s16x8*)(Wp1h + wo);
        const s16x8 bl = *(const s16x8*)(Wp1l + wo);
        #pragma unroll
        for (int m = 0; m < 8; ++m) {
            const s16x8 a = *(const s16x8*)((const char*)lds_u +
                (((u32)((m * 16 + c) * 512 + g * 16 + ks * 64)) ^ swzA));
            acc[m] = mfma16(a, bh, acc[m]);
            acc[m] = mfma16(a, bl, acc[m]);
        }
    }

    // write half-1 (cols 128..255); disjoint bytes from half-0 reads -> no barrier
    {
        uint4 ua = make_uint4(cvt_pk_bf16(h1a.x, h1a.y), cvt_pk_bf16(h1a.z, h1a.w),
                              cvt_pk_bf16(h1b.x, h1b.y), cvt_pk_bf16(h1b.z, h1b.w));
        uint4 ub = make_uint4(cvt_pk_bf16(h1c.x, h1c.y), cvt_pk_bf16(h1c.z, h1c.w),
                              cvt_pk_bf16(h1d.x, h1d.y), cvt_pk_bf16(h1d.z, h1d.w));
        char* dst = (char*)lds_u;
        *(uint4*)(dst + ((sbb + 256 + scol0 * 2 + 0) ^ ssz)) = ua;
        *(uint4*)(dst + ((sbb + 256 + scol0 * 2 + 16) ^ ssz)) = ub;
    }
    __syncthreads();   // half-1 ready

    // ================= GEMM1b: ks 4..7 (k-cols 128..255) =================
    #pragma unroll
    for (int ks = 4; ks < 8; ++ks) {
        const int wo = wbase + ks * 512 + lane * 8;
        const s16x8 bh = *(const s16x8*)(Wp1h + wo);
        const s16x8 bl = *(const s16x8*)(Wp1l + wo);
        #pragma unroll
        for (int m = 0; m < 8; ++m) {
            const s16x8 a = *(const s16x8*)((const char*)lds_u +
                (((u32)((m * 16 + c) * 512 + g * 16 + ks * 64)) ^ swzA));
            acc[m] = mfma16(a, bh, acc[m]);
            acc[m] = mfma16(a, bl, acc[m]);
        }
    }
    __syncthreads();   // all hist reads done; region reusable for Ihi

    // ---- epilogue 1: z -> hi/lo bf16 (pair-pack via shfl), Ihi over hist, Ilo above
    {
        char* Ihi_b = (char*)lds_u;
        char* Ilo_b = (char*)lds_u + 65536;
        const u32 ocol2 = (u32)((o & ~1) * 2);
        #pragma unroll
        for (int m = 0; m < 8; ++m) {
            #pragma unroll
            for (int r = 0; r < 4; ++r) {
                const int row = m * 16 + g * 4 + r;
                float z = acc[m][r] + cpv + dtl[row] * wtv + dll[row] * wlv;
                float zsw = __shfl_xor(z, 1, 64);
                float z0 = (c & 1) ? zsw : z;
                float z1 = (c & 1) ? z : zsw;
                u32 hi2 = cvt_pk_bf16(z0, z1);
                const u32 byteoff = ((u32)(row * 512) + ocol2) ^ ((u32)((row & 7) << 4));
                if (!(c & 1)) {
                    *(u32*)(Ihi_b + byteoff) = hi2;
                } else {
                    float h0 = __builtin_bit_cast(float, hi2 << 16);
                    float h1 = __builtin_bit_cast(float, hi2 & 0xFFFF0000u);
                    u32 lo2 = cvt_pk_bf16(z0 - h0, z1 - h1);
                    *(u32*)(Ilo_b + byteoff) = lo2;
                }
            }
        }
    }
    __syncthreads();   // Ihi/Ilo ready

    // ================= GEMM2: z = (Ihi+Ilo) @ (Wh+Wl)^T (3-pass) =================
    f32x4 acc2[8];
    #pragma unroll
    for (int m = 0; m < 8; ++m) acc2[m] = fz;
    {
        const char* Ihi_b = (const char*)lds_u;
        const char* Ilo_b = (const char*)lds_u + 65536;
        #pragma unroll
        for (int ks = 0; ks < 8; ++ks) {
            const int wo = wbase + ks * 512 + lane * 8;
            const s16x8 bh = *(const s16x8*)(Wp2h + wo);
            const s16x8 bl = *(const s16x8*)(Wp2l + wo);
            #pragma unroll
            for (int m = 0; m < 8; ++m) {
                const u32 ad = ((u32)((m * 16 + c) * 512 + g * 16 + ks * 64)) ^ swzA;
                const s16x8 ah = *(const s16x8*)(Ihi_b + ad);
                const s16x8 al = *(const s16x8*)(Ilo_b + ad);
                acc2[m] = mfma16(ah, bh, acc2[m]);
                acc2[m] = mfma16(ah, bl, acc2[m]);
                acc2[m] = mfma16(al, bh, acc2[m]);
            }
        }
    }

    // ---- epilogue 2: tanh, dot v, reduce over c, then over waves -> scores ------
    #pragma unroll
    for (int m = 0; m < 8; ++m) {
        #pragma unroll
        for (int r = 0; r < 4; ++r) {
            float z = acc2[m][r] + bov;
            float s = fast_tanh(z) * vvv;
            s += __shfl_xor(s, 1, 64);
            s += __shfl_xor(s, 2, 64);
            s += __shfl_xor(s, 4, 64);
            s += __shfl_xor(s, 8, 64);
            if (c == 0) sc_part[w][m * 16 + g * 4 + r] = s;
        }
    }
    __syncthreads();
    if (tid < TT) {
        float s = 0.f;
        #pragma unroll
        for (int ww = 0; ww < 16; ++ww) s += sc_part[ww][tid];
        scores[b * Tdim + t0 + tid] = s;
    }
}

// ---------------- pass 2: softmax + alpha + s_t = alpha^T . hist ----------------
__global__ __launch_bounds__(512) void finish_kernel(
        const float* __restrict__ hist, float* __restrict__ out) {
    const int b = blockIdx.x;
    const int tid = threadIdx.x;
    const int w = tid >> 6, lane = tid & 63;
    __shared__ float al_sh[Tdim];
    __shared__ float wred[4], wsum[4];
    __shared__ float part[Hdim];

    float* scores = out + Bdim * Hdim;
    float sc = 0.f;
    if (tid < Tdim) {
        sc = scores[b * Tdim + tid];
        float mx = sc;
        #pragma unroll
        for (int d = 1; d < 64; d <<= 1) mx = fmaxf(mx, __shfl_xor(mx, d, 64));
        if (lane == 0) wred[w] = mx;
    }
    __syncthreads();
    const float mx = fmaxf(fmaxf(wred[0], wred[1]), fmaxf(wred[2], wred[3]));
    float e = 0.f;
    if (tid < Tdim) {
        e = __expf(sc - mx);
        float ss = e;
        #pragma unroll
        for (int d = 1; d < 64; d <<= 1) ss += __shfl_xor(ss, d, 64);
        if (lane == 0) wsum[w] = ss;
    }
    __syncthreads();
    const float l = wsum[0] + wsum[1] + wsum[2] + wsum[3];
    if (tid < Tdim) {
        const float a = e / l;
        al_sh[tid] = a;
        scores[b * Tdim + tid] = a;   // alpha output (in-place over scores)
    }
    __syncthreads();

    const int h = tid & 255, half = tid >> 8;
    const float* hp = hist + (size_t)b * (Tdim * Hdim) + (size_t)half * 128 * Hdim + h;
    float s0 = 0.f, s1 = 0.f, s2 = 0.f, s3 = 0.f;
    #pragma unroll 4
    for (int t = 0; t < 128; t += 4) {
        const int tb = half * 128 + t;
        s0 += al_sh[tb + 0] * hp[(size_t)(t + 0) * Hdim];
        s1 += al_sh[tb + 1] * hp[(size_t)(t + 1) * Hdim];
        s2 += al_sh[tb + 2] * hp[(size_t)(t + 2) * Hdim];
        s3 += al_sh[tb + 3] * hp[(size_t)(t + 3) * Hdim];
    }
    const float s = (s0 + s1) + (s2 + s3);
    if (half == 0) part[h] = s;
    __syncthreads();
    if (half == 1) out[b * Hdim + h] = part[h] + s;
}

extern "C" void kernel_launch(void* const* d_in, const int* in_sizes, int n_in,
                              void* d_out, int out_size, void* d_ws, size_t ws_size,
                              hipStream_t stream) {
    const float* h_tilde = (const float*)d_in[0];
    const float* c_t     = (const float*)d_in[1];
    const float* hist    = (const float*)d_in[2];
    const float* dT      = (const float*)d_in[3];
    const float* dL      = (const float*)d_in[4];
    const float* W_I     = (const float*)d_in[5];
    const float* W_Ih    = (const float*)d_in[6];
    const float* W_I1T   = (const float*)d_in[7];
    const float* W_I1L   = (const float*)d_in[8];
    const float* b_I     = (const float*)d_in[9];
    const float* W_oI    = (const float*)d_in[10];
    const float* b_oI    = (const float*)d_in[11];
    const float* v_t     = (const float*)d_in[12];
    float* out = (float*)d_out;

    char* ws = (char*)d_ws;
    float* cp  = (float*)ws;                          // 512 KB
    u16* Wp1h = (u16*)(ws + 524288);                  // 128 KB each
    u16* Wp1l = (u16*)(ws + 524288 + 131072);
    u16* Wp2h = (u16*)(ws + 524288 + 2 * 131072);
    u16* Wp2l = (u16*)(ws + 524288 + 3 * 131072);
    float* scores = out + Bdim * Hdim;                // raw scores into alpha slot

    prep_weights<<<dim3(256), dim3(256), 0, stream>>>(W_Ih, W_oI, Wp1h, Wp1l, Wp2h, Wp2l);
    cp_kernel<<<dim3(Bdim), dim3(256), 0, stream>>>(h_tilde, c_t, W_I, b_I, cp);
    scores_kernel<<<dim3(Bdim * NTILE), dim3(NTHR), 0, stream>>>(
        hist, dT, dL, cp, Wp1h, Wp1l, Wp2h, Wp2l, W_I1T, W_I1L, b_oI, v_t, scores);
    finish_kernel<<<dim3(Bdim), dim3(512), 0, stream>>>(hist, out);
}

// Round 7
// 189.989 us; speedup vs baseline: 2.5747x; 1.1004x over previous
//
#include <hip/hip_runtime.h>
#include <hip/hip_bf16.h>

#define Hdim 256
#define Tdim 256
#define Bdim 512
#define TT   128
#define NTILE (Tdim / TT)   // 2
#define NTHR 512

typedef __attribute__((ext_vector_type(8))) short s16x8;
typedef __attribute__((ext_vector_type(4))) float f32x4;
typedef unsigned short u16;
typedef unsigned int u32;

__device__ __forceinline__ u16 f2bf_rne(float x) {
    u32 u = __builtin_bit_cast(u32, x);
    u32 r = u + 0x7FFFu + ((u >> 16) & 1u);
    return (u16)(r >> 16);
}
__device__ __forceinline__ float bf2f(u16 h) {
    u32 u = ((u32)h) << 16;
    return __builtin_bit_cast(float, u);
}
__device__ __forceinline__ u32 cvt_pk_bf16(float lo, float hi) {
    u32 r;
    asm("v_cvt_pk_bf16_f32 %0, %1, %2" : "=v"(r) : "v"(lo), "v"(hi));
    return r;
}
__device__ __forceinline__ f32x4 mfma16(s16x8 a, s16x8 b, f32x4 c) {
    return __builtin_amdgcn_mfma_f32_16x16x32_bf16(a, b, c, 0, 0, 0);
}
__device__ __forceinline__ float fast_tanh(float z) {
    float e = __expf(2.0f * z);
    return 1.0f - 2.0f / (e + 1.0f);
}

// ---------------- prep: split weights into bf16 hi/lo, packed B-fragment layout --
// dst = o16*4096 + ks*512 + g*128 + c*8 + j  (lane*8 per (o16,ks) frag -> coalesced)
__global__ __launch_bounds__(256) void prep_weights(
        const float* __restrict__ W_Ih, const float* __restrict__ W_oI,
        u16* __restrict__ Wp1h, u16* __restrict__ Wp1l,
        u16* __restrict__ Wp2h, u16* __restrict__ Wp2l) {
    int idx = blockIdx.x * 256 + threadIdx.x;   // = o*256 + k
    if (idx >= Hdim * Hdim) return;
    int o = idx >> 8, k = idx & 255;
    int dst = (o >> 4) * 4096 + (k >> 5) * 512 + ((k >> 3) & 3) * 128 + (o & 15) * 8 + (k & 7);
    float w = W_Ih[idx];
    u16 hi = f2bf_rne(w);
    Wp1h[dst] = hi;
    Wp1l[dst] = f2bf_rne(w - bf2f(hi));
    w = W_oI[idx];
    hi = f2bf_rne(w);
    Wp2h[dst] = hi;
    Wp2l[dst] = f2bf_rne(w - bf2f(hi));
}

// ---------------- prep: cp[b,o] = h_hat @ W_I^T + b_I ----------------
__global__ __launch_bounds__(256) void cp_kernel(
        const float* __restrict__ h_tilde, const float* __restrict__ c_t,
        const float* __restrict__ W_I, const float* __restrict__ b_I,
        float* __restrict__ cp) {
    int b = blockIdx.x;
    int tid = threadIdx.x, w = tid >> 6, lane = tid & 63;
    __shared__ float hh[2 * Hdim];
    for (int i = tid; i < 2 * Hdim; i += 256)
        hh[i] = (i < Hdim) ? h_tilde[b * Hdim + i] : c_t[b * Hdim + i - Hdim];
    __syncthreads();
    for (int o = w; o < Hdim; o += 4) {
        float s = 0.f;
        const float* wr = W_I + (size_t)o * (2 * Hdim);
        #pragma unroll
        for (int k = lane; k < 2 * Hdim; k += 64) s += hh[k] * wr[k];
        #pragma unroll
        for (int d = 1; d < 64; d <<= 1) s += __shfl_xor(s, d, 64);
        if (lane == 0) cp[b * Hdim + o] = s + b_I[o];
    }
}

// ---------------- pass 1: scores for a 128-row tile per block ----------------
// 512 threads = 8 waves (2/SIMD -> 128-reg cap, spill-free envelope per r5).
// Wave w owns o-cols [w*32, w*32+32) (n=0,1), m = 0..7 row-frags (TT=128).
// LDS: [0,64K) hist bf16 (GEMM1 A) -> reused as Ihi after GEMM1; [64K,128K) Ilo.
// ~133KB -> 1 block/CU. Weight L2 traffic 512KB/block x 1024 blocks = 512MB.
__global__ __launch_bounds__(NTHR) void scores_kernel(
        const float* __restrict__ hist, const float* __restrict__ dT,
        const float* __restrict__ dL, const float* __restrict__ cp,
        const u16* __restrict__ Wp1h, const u16* __restrict__ Wp1l,
        const u16* __restrict__ Wp2h, const u16* __restrict__ Wp2l,
        const float* __restrict__ wI1T, const float* __restrict__ wI1L,
        const float* __restrict__ b_oI, const float* __restrict__ v_t,
        float* __restrict__ scores) {
    __shared__ u16 lds_u[2 * TT * Hdim];       // 128 KB: hist/Ihi + Ilo
    __shared__ float dtl[TT], dll[TT];         // 1 KB
    __shared__ float sc_part[8][TT];           // 4 KB

    const int bid = blockIdx.x;
    const int b = bid >> 1;                    // NTILE = 2
    const int t0 = (bid & 1) * TT;
    const int tid = threadIdx.x;
    const int w = tid >> 6, lane = tid & 63;
    const int c = lane & 15, g = lane >> 4;
    const int ob = w * 32;

    // per-lane epilogue constants (n = 0,1 -> o = ob + n*16 + c)
    float cpv[2], wtv[2], wlv[2], bov[2], vvv[2];
    #pragma unroll
    for (int n = 0; n < 2; ++n) {
        const int o = ob + n * 16 + c;
        cpv[n] = cp[b * Hdim + o];
        wtv[n] = wI1T[o];
        wlv[n] = wI1L[o];
        bov[n] = b_oI[o];
        vvv[n] = v_t[o];
    }
    if (tid < TT) {
        dtl[tid] = dT[b * Tdim + t0 + tid];
        dll[tid] = dL[b * Tdim + t0 + tid];
    }

    // ---- stage hist tile: 128 rows x 256 cols fp32 -> bf16 swizzled ------------
    // 4 threads per row; chunk ch covers cols [ch*64, ch*64+64); thread j=tid&3
    // loads 16 floats at ch*64 + j*16 -> 256B contiguous per row-chunk (coalesced).
    {
        const int srow = tid >> 2;
        const int sj = tid & 3;
        const float* srcb = hist + ((size_t)b * Tdim + t0 + srow) * Hdim;
        const u32 sbb = (u32)(srow * 512);
        const u32 ssz = (u32)((srow & 7) << 4);
        char* dst = (char*)lds_u;
        #pragma unroll
        for (int ch = 0; ch < 4; ++ch) {
            const int col = ch * 64 + sj * 16;
            float4 f0 = *(const float4*)(srcb + col + 0);
            float4 f1 = *(const float4*)(srcb + col + 4);
            float4 f2 = *(const float4*)(srcb + col + 8);
            float4 f3 = *(const float4*)(srcb + col + 12);
            uint4 ua = make_uint4(cvt_pk_bf16(f0.x, f0.y), cvt_pk_bf16(f0.z, f0.w),
                                  cvt_pk_bf16(f1.x, f1.y), cvt_pk_bf16(f1.z, f1.w));
            uint4 ub = make_uint4(cvt_pk_bf16(f2.x, f2.y), cvt_pk_bf16(f2.z, f2.w),
                                  cvt_pk_bf16(f3.x, f3.y), cvt_pk_bf16(f3.z, f3.w));
            *(uint4*)(dst + ((sbb + (u32)(col * 2) + 0) ^ ssz)) = ua;
            *(uint4*)(dst + ((sbb + (u32)(col * 2) + 16) ^ ssz)) = ub;
        }
    }
    __syncthreads();

    const f32x4 fz = {0.f, 0.f, 0.f, 0.f};
    const u32 swzA = (u32)((c & 7) << 4);
    const int wobg = w * 2;

    // ================= GEMM1: I = hist @ (Wh+Wl)^T (2-pass split bf16) ==========
    f32x4 acc[8][2];
    #pragma unroll
    for (int m = 0; m < 8; ++m) { acc[m][0] = fz; acc[m][1] = fz; }
    {
        const char* hb = (const char*)lds_u;
        #pragma unroll
        for (int ks = 0; ks < 8; ++ks) {
            // hoist both n-slices' B-frags (16 regs); A loaded per-m (4 regs live)
            const int wo0 = (wobg + 0) * 4096 + ks * 512 + lane * 8;
            const int wo1 = (wobg + 1) * 4096 + ks * 512 + lane * 8;
            const s16x8 bh0 = *(const s16x8*)(Wp1h + wo0);
            const s16x8 bl0 = *(const s16x8*)(Wp1l + wo0);
            const s16x8 bh1 = *(const s16x8*)(Wp1h + wo1);
            const s16x8 bl1 = *(const s16x8*)(Wp1l + wo1);
            #pragma unroll
            for (int m = 0; m < 8; ++m) {
                const s16x8 a = *(const s16x8*)(hb +
                    (((u32)((m * 16 + c) * 512 + g * 16 + ks * 64)) ^ swzA));
                acc[m][0] = mfma16(a, bh0, acc[m][0]);
                acc[m][0] = mfma16(a, bl0, acc[m][0]);
                acc[m][1] = mfma16(a, bh1, acc[m][1]);
                acc[m][1] = mfma16(a, bl1, acc[m][1]);
            }
        }
    }
    __syncthreads();   // all hist reads done; region reusable for Ihi

    // ---- epilogue 1: z -> hi/lo bf16 (pair-pack via shfl), Ihi over hist, Ilo above
    {
        char* Ihi_b = (char*)lds_u;
        char* Ilo_b = (char*)lds_u + 65536;
        #pragma unroll
        for (int n = 0; n < 2; ++n) {
            const int o = ob + n * 16 + c;
            const u32 ocol2 = (u32)((o & ~1) * 2);
            #pragma unroll
            for (int m = 0; m < 8; ++m) {
                #pragma unroll
                for (int r = 0; r < 4; ++r) {
                    const int row = m * 16 + g * 4 + r;
                    float z = acc[m][n][r] + cpv[n] + dtl[row] * wtv[n] + dll[row] * wlv[n];
                    float zsw = __shfl_xor(z, 1, 64);
                    float z0 = (c & 1) ? zsw : z;
                    float z1 = (c & 1) ? z : zsw;
                    u32 hi2 = cvt_pk_bf16(z0, z1);
                    const u32 byteoff = ((u32)(row * 512) + ocol2) ^ ((u32)((row & 7) << 4));
                    if (!(c & 1)) {
                        *(u32*)(Ihi_b + byteoff) = hi2;
                    } else {
                        float h0 = __builtin_bit_cast(float, hi2 << 16);
                        float h1 = __builtin_bit_cast(float, hi2 & 0xFFFF0000u);
                        u32 lo2 = cvt_pk_bf16(z0 - h0, z1 - h1);
                        *(u32*)(Ilo_b + byteoff) = lo2;
                    }
                }
            }
        }
    }
    __syncthreads();   // Ihi/Ilo ready

    // ================= GEMM2: z = (Ihi+Ilo) @ (Wh+Wl)^T (3-pass) =================
    f32x4 acc2[8][2];
    #pragma unroll
    for (int m = 0; m < 8; ++m) { acc2[m][0] = fz; acc2[m][1] = fz; }
    {
        const char* Ihi_b = (const char*)lds_u;
        const char* Ilo_b = (const char*)lds_u + 65536;
        #pragma unroll
        for (int ks = 0; ks < 8; ++ks) {
            const int wo0 = (wobg + 0) * 4096 + ks * 512 + lane * 8;
            const int wo1 = (wobg + 1) * 4096 + ks * 512 + lane * 8;
            const s16x8 bh0 = *(const s16x8*)(Wp2h + wo0);
            const s16x8 bl0 = *(const s16x8*)(Wp2l + wo0);
            const s16x8 bh1 = *(const s16x8*)(Wp2h + wo1);
            const s16x8 bl1 = *(const s16x8*)(Wp2l + wo1);
            #pragma unroll
            for (int m = 0; m < 8; ++m) {
                const u32 ad = ((u32)((m * 16 + c) * 512 + g * 16 + ks * 64)) ^ swzA;
                const s16x8 ah = *(const s16x8*)(Ihi_b + ad);
                const s16x8 al = *(const s16x8*)(Ilo_b + ad);
                acc2[m][0] = mfma16(ah, bh0, acc2[m][0]);
                acc2[m][0] = mfma16(ah, bl0, acc2[m][0]);
                acc2[m][0] = mfma16(al, bh0, acc2[m][0]);
                acc2[m][1] = mfma16(ah, bh1, acc2[m][1]);
                acc2[m][1] = mfma16(ah, bl1, acc2[m][1]);
                acc2[m][1] = mfma16(al, bh1, acc2[m][1]);
            }
        }
    }

    // ---- epilogue 2: tanh, dot v, reduce over c, then over waves -> scores ------
    #pragma unroll
    for (int m = 0; m < 8; ++m) {
        #pragma unroll
        for (int r = 0; r < 4; ++r) {
            float s = 0.f;
            #pragma unroll
            for (int n = 0; n < 2; ++n) {
                float z = acc2[m][n][r] + bov[n];
                s += fast_tanh(z) * vvv[n];
            }
            s += __shfl_xor(s, 1, 64);
            s += __shfl_xor(s, 2, 64);
            s += __shfl_xor(s, 4, 64);
            s += __shfl_xor(s, 8, 64);
            if (c == 0) sc_part[w][m * 16 + g * 4 + r] = s;
        }
    }
    __syncthreads();
    if (tid < TT) {
        float s = 0.f;
        #pragma unroll
        for (int ww = 0; ww < 8; ++ww) s += sc_part[ww][tid];
        scores[b * Tdim + t0 + tid] = s;
    }
}

// ---------------- pass 2: softmax + alpha + s_t = alpha^T . hist ----------------
__global__ __launch_bounds__(512) void finish_kernel(
        const float* __restrict__ hist, float* __restrict__ out) {
    const int b = blockIdx.x;
    const int tid = threadIdx.x;
    const int w = tid >> 6, lane = tid & 63;
    __shared__ float al_sh[Tdim];
    __shared__ float wred[4], wsum[4];
    __shared__ float part[Hdim];

    float* scores = out + Bdim * Hdim;
    float sc = 0.f;
    if (tid < Tdim) {
        sc = scores[b * Tdim + tid];
        float mx = sc;
        #pragma unroll
        for (int d = 1; d < 64; d <<= 1) mx = fmaxf(mx, __shfl_xor(mx, d, 64));
        if (lane == 0) wred[w] = mx;
    }
    __syncthreads();
    const float mx = fmaxf(fmaxf(wred[0], wred[1]), fmaxf(wred[2], wred[3]));
    float e = 0.f;
    if (tid < Tdim) {
        e = __expf(sc - mx);
        float ss = e;
        #pragma unroll
        for (int d = 1; d < 64; d <<= 1) ss += __shfl_xor(ss, d, 64);
        if (lane == 0) wsum[w] = ss;
    }
    __syncthreads();
    const float l = wsum[0] + wsum[1] + wsum[2] + wsum[3];
    if (tid < Tdim) {
        const float a = e / l;
        al_sh[tid] = a;
        scores[b * Tdim + tid] = a;   // alpha output (in-place over scores)
    }
    __syncthreads();

    const int h = tid & 255, half = tid >> 8;
    const float* hp = hist + (size_t)b * (Tdim * Hdim) + (size_t)half * 128 * Hdim + h;
    float s0 = 0.f, s1 = 0.f, s2 = 0.f, s3 = 0.f;
    #pragma unroll 4
    for (int t = 0; t < 128; t += 4) {
        const int tb = half * 128 + t;
        s0 += al_sh[tb + 0] * hp[(size_t)(t + 0) * Hdim];
        s1 += al_sh[tb + 1] * hp[(size_t)(t + 1) * Hdim];
        s2 += al_sh[tb + 2] * hp[(size_t)(t + 2) * Hdim];
        s3 += al_sh[tb + 3] * hp[(size_t)(t + 3) * Hdim];
    }
    const float s = (s0 + s1) + (s2 + s3);
    if (half == 0) part[h] = s;
    __syncthreads();
    if (half == 1) out[b * Hdim + h] = part[h] + s;
}

extern "C" void kernel_launch(void* const* d_in, const int* in_sizes, int n_in,
                              void* d_out, int out_size, void* d_ws, size_t ws_size,
                              hipStream_t stream) {
    const float* h_tilde = (const float*)d_in[0];
    const float* c_t     = (const float*)d_in[1];
    const float* hist    = (const float*)d_in[2];
    const float* dT      = (const float*)d_in[3];
    const float* dL      = (const float*)d_in[4];
    const float* W_I     = (const float*)d_in[5];
    const float* W_Ih    = (const float*)d_in[6];
    const float* W_I1T   = (const float*)d_in[7];
    const float* W_I1L   = (const float*)d_in[8];
    const float* b_I     = (const float*)d_in[9];
    const float* W_oI    = (const float*)d_in[10];
    const float* b_oI    = (const float*)d_in[11];
    const float* v_t     = (const float*)d_in[12];
    float* out = (float*)d_out;

    char* ws = (char*)d_ws;
    float* cp  = (float*)ws;                          // 512 KB
    u16* Wp1h = (u16*)(ws + 524288);                  // 128 KB each
    u16* Wp1l = (u16*)(ws + 524288 + 131072);
    u16* Wp2h = (u16*)(ws + 524288 + 2 * 131072);
    u16* Wp2l = (u16*)(ws + 524288 + 3 * 131072);
    float* scores = out + Bdim * Hdim;                // raw scores into alpha slot

    prep_weights<<<dim3(256), dim3(256), 0, stream>>>(W_Ih, W_oI, Wp1h, Wp1l, Wp2h, Wp2l);
    cp_kernel<<<dim3(Bdim), dim3(256), 0, stream>>>(h_tilde, c_t, W_I, b_I, cp);
    scores_kernel<<<dim3(Bdim * NTILE), dim3(NTHR), 0, stream>>>(
        hist, dT, dL, cp, Wp1h, Wp1l, Wp2h, Wp2l, W_I1T, W_I1L, b_oI, v_t, scores);
    finish_kernel<<<dim3(Bdim), dim3(512), 0, stream>>>(hist, out);
}

// Round 8
// 189.685 us; speedup vs baseline: 2.5789x; 1.0016x over previous
//
#include <hip/hip_runtime.h>
#include <hip/hip_bf16.h>

#define Hdim 256
#define Tdim 256
#define Bdim 512
#define TT   64
#define NTILE (Tdim / TT)   // 4
#define NTHR 256

typedef __attribute__((ext_vector_type(8))) short s16x8;
typedef __attribute__((ext_vector_type(4))) float f32x4;
typedef unsigned short u16;
typedef unsigned int u32;

__device__ __forceinline__ u16 f2bf_rne(float x) {
    u32 u = __builtin_bit_cast(u32, x);
    u32 r = u + 0x7FFFu + ((u >> 16) & 1u);
    return (u16)(r >> 16);
}
__device__ __forceinline__ float bf2f(u16 h) {
    u32 u = ((u32)h) << 16;
    return __builtin_bit_cast(float, u);
}
__device__ __forceinline__ u32 cvt_pk_bf16(float lo, float hi) {
    u32 r;
    asm("v_cvt_pk_bf16_f32 %0, %1, %2" : "=v"(r) : "v"(lo), "v"(hi));
    return r;
}
__device__ __forceinline__ f32x4 mfma16(s16x8 a, s16x8 b, f32x4 c) {
    return __builtin_amdgcn_mfma_f32_16x16x32_bf16(a, b, c, 0, 0, 0);
}
__device__ __forceinline__ float fast_tanh(float z) {
    float e = __expf(2.0f * z);
    return 1.0f - 2.0f / (e + 1.0f);
}

// ---------------- prep: split weights into bf16 hi/lo, packed B-fragment layout --
// dst = o16*4096 + ks*512 + g*128 + c*8 + j  (lane*8 per (o16,ks) frag -> coalesced)
__global__ __launch_bounds__(256) void prep_weights(
        const float* __restrict__ W_Ih, const float* __restrict__ W_oI,
        u16* __restrict__ Wp1h, u16* __restrict__ Wp1l,
        u16* __restrict__ Wp2h, u16* __restrict__ Wp2l) {
    int idx = blockIdx.x * 256 + threadIdx.x;   // = o*256 + k
    if (idx >= Hdim * Hdim) return;
    int o = idx >> 8, k = idx & 255;
    int dst = (o >> 4) * 4096 + (k >> 5) * 512 + ((k >> 3) & 3) * 128 + (o & 15) * 8 + (k & 7);
    float w = W_Ih[idx];
    u16 hi = f2bf_rne(w);
    Wp1h[dst] = hi;
    Wp1l[dst] = f2bf_rne(w - bf2f(hi));
    w = W_oI[idx];
    hi = f2bf_rne(w);
    Wp2h[dst] = hi;
    Wp2l[dst] = f2bf_rne(w - bf2f(hi));
}

// ---------------- prep: cp[b,o] = h_hat @ W_I^T + b_I ----------------
__global__ __launch_bounds__(256) void cp_kernel(
        const float* __restrict__ h_tilde, const float* __restrict__ c_t,
        const float* __restrict__ W_I, const float* __restrict__ b_I,
        float* __restrict__ cp) {
    int b = blockIdx.x;
    int tid = threadIdx.x, w = tid >> 6, lane = tid & 63;
    __shared__ float hh[2 * Hdim];
    for (int i = tid; i < 2 * Hdim; i += 256)
        hh[i] = (i < Hdim) ? h_tilde[b * Hdim + i] : c_t[b * Hdim + i - Hdim];
    __syncthreads();
    for (int o = w; o < Hdim; o += 4) {
        float s = 0.f;
        const float* wr = W_I + (size_t)o * (2 * Hdim);
        #pragma unroll
        for (int k = lane; k < 2 * Hdim; k += 64) s += hh[k] * wr[k];
        #pragma unroll
        for (int d = 1; d < 64; d <<= 1) s += __shfl_xor(s, d, 64);
        if (lane == 0) cp[b * Hdim + o] = s + b_I[o];
    }
}

// ---------------- pass 1: scores for a 64-row tile per 256-thread block ----------
// 4 waves; wave w owns o-cols [w*64, w*64+64) (n=0..3), m=0..3 row-frags.
// LDS ~71KB -> 2 blocks/CU resident: two INDEPENDENT 4-wave barrier domains per
// CU so one block's staging/epilogue/barrier-drain overlaps the other's GEMMs
// (r7 had one 8-wave domain -> every barrier drained the whole CU).
// LDS: [0,32K) hist bf16 -> reused as Ihi after GEMM1; [32K,64K) Ilo.
__global__ __launch_bounds__(NTHR) void scores_kernel(
        const float* __restrict__ hist, const float* __restrict__ dT,
        const float* __restrict__ dL, const float* __restrict__ cp,
        const u16* __restrict__ Wp1h, const u16* __restrict__ Wp1l,
        const u16* __restrict__ Wp2h, const u16* __restrict__ Wp2l,
        const float* __restrict__ wI1T, const float* __restrict__ wI1L,
        const float* __restrict__ b_oI, const float* __restrict__ v_t,
        float* __restrict__ scores) {
    __shared__ u16 lds_u[2 * TT * Hdim];       // 64 KB: hist/Ihi + Ilo
    __shared__ float cpb[Hdim], wTb[Hdim], wLb[Hdim], bob[Hdim], vvb[Hdim]; // 5 KB
    __shared__ float dtl[TT], dll[TT];         // 0.5 KB
    __shared__ float sc_part[4][TT];           // 1 KB

    const int bid = blockIdx.x;
    const int b = bid >> 2;                    // NTILE = 4
    const int t0 = (bid & 3) * TT;
    const int tid = threadIdx.x;
    const int w = tid >> 6, lane = tid & 63;
    const int c = lane & 15, g = lane >> 4;
    const int ob = w * 64;                     // wave's 64-col o-slice

    // per-o constants into LDS (keeps register peak low for 128-cap)
    for (int i = tid; i < Hdim; i += NTHR) {
        cpb[i] = cp[b * Hdim + i];
        wTb[i] = wI1T[i];
        wLb[i] = wI1L[i];
        bob[i] = b_oI[i];
        vvb[i] = v_t[i];
    }
    if (tid < TT) {
        dtl[tid] = dT[b * Tdim + t0 + tid];
        dll[tid] = dL[b * Tdim + t0 + tid];
    }

    // ---- stage hist tile: 64 rows x 256 cols fp32 -> bf16 swizzled --------------
    // 4 threads per row; thread j=tid&3 covers cols ch*64 + j*16 (16 floats/chunk).
    {
        const int srow = tid >> 2;
        const int sj = tid & 3;
        const float* srcb = hist + ((size_t)b * Tdim + t0 + srow) * Hdim;
        const u32 sbb = (u32)(srow * 512);
        const u32 ssz = (u32)((srow & 7) << 4);
        char* dst = (char*)lds_u;
        #pragma unroll
        for (int ch = 0; ch < 4; ++ch) {
            const int col = ch * 64 + sj * 16;
            float4 f0 = *(const float4*)(srcb + col + 0);
            float4 f1 = *(const float4*)(srcb + col + 4);
            float4 f2 = *(const float4*)(srcb + col + 8);
            float4 f3 = *(const float4*)(srcb + col + 12);
            uint4 ua = make_uint4(cvt_pk_bf16(f0.x, f0.y), cvt_pk_bf16(f0.z, f0.w),
                                  cvt_pk_bf16(f1.x, f1.y), cvt_pk_bf16(f1.z, f1.w));
            uint4 ub = make_uint4(cvt_pk_bf16(f2.x, f2.y), cvt_pk_bf16(f2.z, f2.w),
                                  cvt_pk_bf16(f3.x, f3.y), cvt_pk_bf16(f3.z, f3.w));
            *(uint4*)(dst + ((sbb + (u32)(col * 2) + 0) ^ ssz)) = ua;
            *(uint4*)(dst + ((sbb + (u32)(col * 2) + 16) ^ ssz)) = ub;
        }
    }
    __syncthreads();

    const f32x4 fz = {0.f, 0.f, 0.f, 0.f};
    const u32 swzA = (u32)((c & 7) << 4);

    // ================= GEMM1: I = hist @ (Wh+Wl)^T (2-pass split bf16) ==========
    f32x4 acc[4][4];
    #pragma unroll
    for (int m = 0; m < 4; ++m)
        #pragma unroll
        for (int n = 0; n < 4; ++n) acc[m][n] = fz;
    {
        const char* hb = (const char*)lds_u;
        #pragma unroll
        for (int ks = 0; ks < 8; ++ks) {
            s16x8 a[4];                        // A-frags hoisted once per ks
            #pragma unroll
            for (int m = 0; m < 4; ++m)
                a[m] = *(const s16x8*)(hb +
                    (((u32)((m * 16 + c) * 512 + g * 16 + ks * 64)) ^ swzA));
            #pragma unroll
            for (int n = 0; n < 4; ++n) {
                const int wo = (w * 4 + n) * 4096 + ks * 512 + lane * 8;
                const s16x8 bh = *(const s16x8*)(Wp1h + wo);
                const s16x8 bl = *(const s16x8*)(Wp1l + wo);
                #pragma unroll
                for (int m = 0; m < 4; ++m) {
                    acc[m][n] = mfma16(a[m], bh, acc[m][n]);
                    acc[m][n] = mfma16(a[m], bl, acc[m][n]);
                }
            }
        }
    }
    __syncthreads();   // all hist reads done; region reusable for Ihi

    // ---- epilogue 1: z -> hi/lo bf16 (pair-pack via shfl), Ihi over hist --------
    {
        char* Ihi_b = (char*)lds_u;
        char* Ilo_b = (char*)lds_u + 32768;
        #pragma unroll
        for (int n = 0; n < 4; ++n) {
            const int o = ob + n * 16 + c;
            const float base_ = cpb[o], wt = wTb[o], wl = wLb[o];
            const u32 ocol2 = (u32)((o & ~1) * 2);
            #pragma unroll
            for (int m = 0; m < 4; ++m) {
                #pragma unroll
                for (int r = 0; r < 4; ++r) {
                    const int row = m * 16 + g * 4 + r;
                    float z = acc[m][n][r] + base_ + dtl[row] * wt + dll[row] * wl;
                    float zsw = __shfl_xor(z, 1, 64);
                    float z0 = (c & 1) ? zsw : z;
                    float z1 = (c & 1) ? z : zsw;
                    u32 hi2 = cvt_pk_bf16(z0, z1);
                    const u32 byteoff = ((u32)(row * 512) + ocol2) ^ ((u32)((row & 7) << 4));
                    if (!(c & 1)) {
                        *(u32*)(Ihi_b + byteoff) = hi2;
                    } else {
                        float h0 = __builtin_bit_cast(float, hi2 << 16);
                        float h1 = __builtin_bit_cast(float, hi2 & 0xFFFF0000u);
                        u32 lo2 = cvt_pk_bf16(z0 - h0, z1 - h1);
                        *(u32*)(Ilo_b + byteoff) = lo2;
                    }
                }
            }
        }
    }
    __syncthreads();   // Ihi/Ilo ready

    // ================= GEMM2: z = (Ihi+Ilo) @ (Wh+Wl)^T (3-pass) =================
    f32x4 acc2[4][4];
    #pragma unroll
    for (int m = 0; m < 4; ++m)
        #pragma unroll
        for (int n = 0; n < 4; ++n) acc2[m][n] = fz;
    {
        const char* Ihi_b = (const char*)lds_u;
        const char* Ilo_b = (const char*)lds_u + 32768;
        #pragma unroll
        for (int ks = 0; ks < 8; ++ks) {
            s16x8 ah[4], al[4];
            #pragma unroll
            for (int m = 0; m < 4; ++m) {
                const u32 ad = ((u32)((m * 16 + c) * 512 + g * 16 + ks * 64)) ^ swzA;
                ah[m] = *(const s16x8*)(Ihi_b + ad);
                al[m] = *(const s16x8*)(Ilo_b + ad);
            }
            #pragma unroll
            for (int n = 0; n < 4; ++n) {
                const int wo = (w * 4 + n) * 4096 + ks * 512 + lane * 8;
                const s16x8 bh = *(const s16x8*)(Wp2h + wo);
                const s16x8 bl = *(const s16x8*)(Wp2l + wo);
                #pragma unroll
                for (int m = 0; m < 4; ++m) {
                    acc2[m][n] = mfma16(ah[m], bh, acc2[m][n]);
                    acc2[m][n] = mfma16(ah[m], bl, acc2[m][n]);
                    acc2[m][n] = mfma16(al[m], bh, acc2[m][n]);
                }
            }
        }
    }

    // ---- epilogue 2: tanh, dot v, reduce over c, then over waves -> scores ------
    {
        float bov[4], vvv[4];
        #pragma unroll
        for (int n = 0; n < 4; ++n) {
            const int o = ob + n * 16 + c;
            bov[n] = bob[o];
            vvv[n] = vvb[o];
        }
        #pragma unroll
        for (int m = 0; m < 4; ++m) {
            #pragma unroll
            for (int r = 0; r < 4; ++r) {
                float s = 0.f;
                #pragma unroll
                for (int n = 0; n < 4; ++n) {
                    float z = acc2[m][n][r] + bov[n];
                    s += fast_tanh(z) * vvv[n];
                }
                s += __shfl_xor(s, 1, 64);
                s += __shfl_xor(s, 2, 64);
                s += __shfl_xor(s, 4, 64);
                s += __shfl_xor(s, 8, 64);
                if (c == 0) sc_part[w][m * 16 + g * 4 + r] = s;
            }
        }
    }
    __syncthreads();
    if (tid < TT) {
        float s = sc_part[0][tid] + sc_part[1][tid] + sc_part[2][tid] + sc_part[3][tid];
        scores[b * Tdim + t0 + tid] = s;
    }
}

// ---------------- pass 2: softmax + alpha + s_t = alpha^T . hist ----------------
__global__ __launch_bounds__(512) void finish_kernel(
        const float* __restrict__ hist, float* __restrict__ out) {
    const int b = blockIdx.x;
    const int tid = threadIdx.x;
    const int w = tid >> 6, lane = tid & 63;
    __shared__ float al_sh[Tdim];
    __shared__ float wred[4], wsum[4];
    __shared__ float part[Hdim];

    float* scores = out + Bdim * Hdim;
    float sc = 0.f;
    if (tid < Tdim) {
        sc = scores[b * Tdim + tid];
        float mx = sc;
        #pragma unroll
        for (int d = 1; d < 64; d <<= 1) mx = fmaxf(mx, __shfl_xor(mx, d, 64));
        if (lane == 0) wred[w] = mx;
    }
    __syncthreads();
    const float mx = fmaxf(fmaxf(wred[0], wred[1]), fmaxf(wred[2], wred[3]));
    float e = 0.f;
    if (tid < Tdim) {
        e = __expf(sc - mx);
        float ss = e;
        #pragma unroll
        for (int d = 1; d < 64; d <<= 1) ss += __shfl_xor(ss, d, 64);
        if (lane == 0) wsum[w] = ss;
    }
    __syncthreads();
    const float l = wsum[0] + wsum[1] + wsum[2] + wsum[3];
    if (tid < Tdim) {
        const float a = e / l;
        al_sh[tid] = a;
        scores[b * Tdim + tid] = a;   // alpha output (in-place over scores)
    }
    __syncthreads();

    const int h = tid & 255, half = tid >> 8;
    const float* hp = hist + (size_t)b * (Tdim * Hdim) + (size_t)half * 128 * Hdim + h;
    float s0 = 0.f, s1 = 0.f, s2 = 0.f, s3 = 0.f;
    #pragma unroll 4
    for (int t = 0; t < 128; t += 4) {
        const int tb = half * 128 + t;
        s0 += al_sh[tb + 0] * hp[(size_t)(t + 0) * Hdim];
        s1 += al_sh[tb + 1] * hp[(size_t)(t + 1) * Hdim];
        s2 += al_sh[tb + 2] * hp[(size_t)(t + 2) * Hdim];
        s3 += al_sh[tb + 3] * hp[(size_t)(t + 3) * Hdim];
    }
    const float s = (s0 + s1) + (s2 + s3);
    if (half == 0) part[h] = s;
    __syncthreads();
    if (half == 1) out[b * Hdim + h] = part[h] + s;
}

extern "C" void kernel_launch(void* const* d_in, const int* in_sizes, int n_in,
                              void* d_out, int out_size, void* d_ws, size_t ws_size,
                              hipStream_t stream) {
    const float* h_tilde = (const float*)d_in[0];
    const float* c_t     = (const float*)d_in[1];
    const float* hist    = (const float*)d_in[2];
    const float* dT      = (const float*)d_in[3];
    const float* dL      = (const float*)d_in[4];
    const float* W_I     = (const float*)d_in[5];
    const float* W_Ih    = (const float*)d_in[6];
    const float* W_I1T   = (const float*)d_in[7];
    const float* W_I1L   = (const float*)d_in[8];
    const float* b_I     = (const float*)d_in[9];
    const float* W_oI    = (const float*)d_in[10];
    const float* b_oI    = (const float*)d_in[11];
    const float* v_t     = (const float*)d_in[12];
    float* out = (float*)d_out;

    char* ws = (char*)d_ws;
    float* cp  = (float*)ws;                          // 512 KB
    u16* Wp1h = (u16*)(ws + 524288);                  // 128 KB each
    u16* Wp1l = (u16*)(ws + 524288 + 131072);
    u16* Wp2h = (u16*)(ws + 524288 + 2 * 131072);
    u16* Wp2l = (u16*)(ws + 524288 + 3 * 131072);
    float* scores = out + Bdim * Hdim;                // raw scores into alpha slot

    prep_weights<<<dim3(256), dim3(256), 0, stream>>>(W_Ih, W_oI, Wp1h, Wp1l, Wp2h, Wp2l);
    cp_kernel<<<dim3(Bdim), dim3(256), 0, stream>>>(h_tilde, c_t, W_I, b_I, cp);
    scores_kernel<<<dim3(Bdim * NTILE), dim3(NTHR), 0, stream>>>(
        hist, dT, dL, cp, Wp1h, Wp1l, Wp2h, Wp2l, W_I1T, W_I1L, b_oI, v_t, scores);
    finish_kernel<<<dim3(Bdim), dim3(512), 0, stream>>>(hist, out);
}